// Round 3
// baseline (1102.011 us; speedup 1.0000x reference)
//
#include <hip/hip_runtime.h>
#include <hip/hip_bf16.h>

// ---------------- JAX threefry2x32 (partitionable) + normal(key=42) --------

__device__ inline unsigned rotl32(unsigned x, unsigned r) {
    return (x << r) | (x >> (32 - r));
}

// threefry2x32 with key (k0,k1)=(0,42); returns both output words.
__device__ inline void threefry2x32_042(unsigned c0, unsigned c1,
                                        unsigned& o0, unsigned& o1) {
    const unsigned k0 = 0u, k1 = 42u;
    unsigned ks[3] = { k0, k1, k0 ^ k1 ^ 0x1BD11BDAu };
    unsigned x0 = c0 + ks[0];
    unsigned x1 = c1 + ks[1];
    const unsigned rotA[4] = {13u, 15u, 26u, 6u};
    const unsigned rotB[4] = {17u, 29u, 16u, 24u};

    #pragma unroll
    for (int i = 0; i < 5; ++i) {
        #pragma unroll
        for (int j = 0; j < 4; ++j) {
            unsigned r = (i & 1) ? rotB[j] : rotA[j];
            x0 += x1;
            x1 = rotl32(x1, r);
            x1 ^= x0;
        }
        x0 += ks[(i + 1) % 3];
        x1 += ks[(i + 2) % 3] + (unsigned)(i + 1);
    }
    o0 = x0; o1 = x1;
}

// XLA ErfInv32 (Giles) — matches jax.lax.erf_inv on f32.
__device__ inline float erfinv_f32(float x) {
    float w = -log1pf(-x * x);
    float p;
    if (w < 5.0f) {
        w -= 2.5f;
        p = 2.81022636e-08f;
        p = fmaf(p, w, 3.43273939e-07f);
        p = fmaf(p, w, -3.5233877e-06f);
        p = fmaf(p, w, -4.39150654e-06f);
        p = fmaf(p, w, 0.00021858087f);
        p = fmaf(p, w, -0.00125372503f);
        p = fmaf(p, w, -0.00417768164f);
        p = fmaf(p, w, 0.246640727f);
        p = fmaf(p, w, 1.50140941f);
    } else {
        w = sqrtf(w) - 3.0f;
        p = -0.000200214257f;
        p = fmaf(p, w, 0.000100950558f);
        p = fmaf(p, w, 0.00134934322f);
        p = fmaf(p, w, -0.00367342844f);
        p = fmaf(p, w, 0.00573950773f);
        p = fmaf(p, w, -0.0076224613f);
        p = fmaf(p, w, 0.00943887047f);
        p = fmaf(p, w, 1.00167406f);
        p = fmaf(p, w, 2.83297682f);
    }
    return p * x;
}

// jax.random.normal(key(42), (256,32))[flat idx] under the modern
// threefry_partitionable=True default: counts = iota(u64), threefry inputs
// (hi32, lo32) = (0, idx), 32-bit word = o0 ^ o1.
__device__ inline float jax_normal_4232(unsigned idx) {
    unsigned o0, o1;
    threefry2x32_042(0u, idx, o0, o1);
    unsigned bits = o0 ^ o1;
    unsigned fb = (bits >> 9) | 0x3f800000u;
    float f = __uint_as_float(fb) - 1.0f;              // [0, 1)
    const float lo = -0.99999994f;                     // nextafter(-1, 0)
    float u = f * (1.0f - lo) + lo;
    u = fmaxf(u, lo);
    return 1.41421356f * erfinv_f32(u);
}

// ---------------- int64/int32 index handling -------------------------------

__device__ inline int idx_at(const void* p, long long i, int is64) {
    return is64 ? (int)((const long long*)p)[i] : ((const int*)p)[i];
}

__global__ __launch_bounds__(256) void detect_idx64(const unsigned* __restrict__ raw,
                                                    int ne, int* flag) {
    __shared__ int nz;
    if (threadIdx.x == 0) nz = 0;
    __syncthreads();
    int stride = ne / 2048;
    if (stride < 1) stride = 1;
    for (int k = threadIdx.x; k < 2048; k += 256) {
        long long j = (long long)k * stride;
        if (j < ne && raw[2 * j + 1] != 0u) nz = 1;
    }
    __syncthreads();
    if (threadIdx.x == 0) flag[0] = (nz == 0) ? 1 : 0;
}

// ---------------- graph kernels -------------------------------------------

__global__ __launch_bounds__(256) void deg_init(float* deg, int n) {
    int i = blockIdx.x * 256 + threadIdx.x;
    if (i < n) deg[i] = 1.0f;
}

__global__ __launch_bounds__(256) void deg_accum(const void* __restrict__ ei,
                                                 const int* __restrict__ flag,
                                                 float* deg, int ne) {
    int i = blockIdx.x * 256 + threadIdx.x;
    int is64 = flag[0];
    if (i < ne) {
        int d = idx_at(ei, (long long)ne + i, is64);   // dst row
        atomicAdd(&deg[d], 1.0f);
    }
}

__global__ __launch_bounds__(256) void deg_to_dinv(float* deg, int n) {
    int i = blockIdx.x * 256 + threadIdx.x;
    if (i < n) deg[i] = rsqrtf(deg[i]);
}

// Y[n][64] = X[n][64] @ W[64][64]   (no bias)
__global__ __launch_bounds__(256) void lin64(const float* __restrict__ X,
                                             const float* __restrict__ W,
                                             float* __restrict__ Y, int nrows) {
    __shared__ float sW[64 * 64];
    __shared__ float sX[4][64];
    int t = threadIdx.x;
    for (int i = t; i < 64 * 64; i += 256) sW[i] = W[i];
    int lane = t & 63;
    int w = t >> 6;
    int row = blockIdx.x * 4 + w;
    if (row < nrows) sX[w][lane] = X[(size_t)row * 64 + lane];
    __syncthreads();
    if (row < nrows) {
        float acc = 0.0f;
        #pragma unroll
        for (int k = 0; k < 64; ++k)
            acc = fmaf(sX[w][k], sW[k * 64 + lane], acc);
        Y[(size_t)row * 64 + lane] = acc;
    }
}

// AGG[i] = Y[i] * dinv[node]^2   (self-loop term)
__global__ __launch_bounds__(256) void agg_init(const float* __restrict__ Y,
                                                const float* __restrict__ dinv,
                                                float* __restrict__ AGG, int total) {
    int i = blockIdx.x * 256 + threadIdx.x;
    if (i < total) {
        float di = dinv[i >> 6];
        AGG[i] = Y[i] * di * di;
    }
}

// AGG[dst] += Y[src] * dinv[src]*dinv[dst], 64 lanes per edge
__global__ __launch_bounds__(256) void gcn_agg_edges(const float* __restrict__ Y,
                                                     const float* __restrict__ dinv,
                                                     const void* __restrict__ ei,
                                                     const int* __restrict__ flag,
                                                     float* __restrict__ AGG, int ne) {
    int t = threadIdx.x;
    int e = blockIdx.x * 4 + (t >> 6);
    int c = t & 63;
    int is64 = flag[0];
    if (e < ne) {
        int s = idx_at(ei, e, is64);                    // src row
        int d = idx_at(ei, (long long)ne + e, is64);    // dst row
        float norm = dinv[s] * dinv[d];
        atomicAdd(&AGG[(size_t)d * 64 + c], Y[(size_t)s * 64 + c] * norm);
    }
}

// X[i] = relu(AGG[i] + b[i%64])
__global__ __launch_bounds__(256) void agg_finish(float* __restrict__ AGG,
                                                  const float* __restrict__ b,
                                                  int total) {
    int i = blockIdx.x * 256 + threadIdx.x;
    if (i < total) AGG[i] = fmaxf(AGG[i] + b[i & 63], 0.0f);
}

__global__ __launch_bounds__(256) void pool_init(float* sums, float* counts, int g) {
    int i = blockIdx.x * 256 + threadIdx.x;
    if (i < g * 64) sums[i] = 0.0f;
    if (i < g) counts[i] = 0.0f;
}

__global__ __launch_bounds__(256) void pool_accum(const float* __restrict__ X,
                                                  const void* __restrict__ batch,
                                                  const int* __restrict__ flag,
                                                  float* __restrict__ sums,
                                                  float* __restrict__ counts, int n) {
    int t = threadIdx.x;
    int node = blockIdx.x * 4 + (t >> 6);
    int c = t & 63;
    int is64 = flag[0];
    if (node < n) {
        int g = idx_at(batch, node, is64);
        atomicAdd(&sums[(size_t)g * 64 + c], X[(size_t)node * 64 + c]);
        if (c == 0) atomicAdd(&counts[g], 1.0f);
    }
}

// One block (64 threads) per graph: pooled -> mu/logvar -> z -> recon
__global__ __launch_bounds__(64) void vae_head(const float* __restrict__ sums,
                                               const float* __restrict__ counts,
                                               const float* __restrict__ Wmu,
                                               const float* __restrict__ bmu,
                                               const float* __restrict__ Wlv,
                                               const float* __restrict__ blv,
                                               const float* __restrict__ Wd1,
                                               const float* __restrict__ bd1,
                                               const float* __restrict__ Wd2,
                                               const float* __restrict__ bd2,
                                               float* __restrict__ out) {
    int g = blockIdx.x;
    int t = threadIdx.x;  // 64 threads
    __shared__ float sp[64];
    __shared__ float sz[32];
    __shared__ float sh[64];

    float cnt = fmaxf(counts[g], 1.0f);
    sp[t] = sums[(size_t)g * 64 + t] / cnt;
    __syncthreads();

    if (t < 32) {
        float mu = bmu[t];
        float lv = blv[t];
        #pragma unroll
        for (int k = 0; k < 64; ++k) {
            float pk = sp[k];
            mu = fmaf(pk, Wmu[k * 32 + t], mu);
            lv = fmaf(pk, Wlv[k * 32 + t], lv);
        }
        unsigned idx = (unsigned)(g * 32 + t);
        float eps = jax_normal_4232(idx);
        float z = fmaf(eps, expf(0.5f * lv), mu);
        sz[t] = z;
        out[16384 + (size_t)g * 32 + t] = mu;       // mu block
        out[24576 + (size_t)g * 32 + t] = lv;       // logvar block
    }
    __syncthreads();

    float h = bd1[t];
    #pragma unroll
    for (int k = 0; k < 32; ++k) h = fmaf(sz[k], Wd1[k * 64 + t], h);
    h = fmaxf(h, 0.0f);
    sh[t] = h;
    __syncthreads();

    float r = bd2[t];
    #pragma unroll
    for (int k = 0; k < 64; ++k) r = fmaf(sh[k], Wd2[k * 64 + t], r);
    out[(size_t)g * 64 + t] = r;                    // recon block
}

// ---------------- launch ----------------------------------------------------

extern "C" void kernel_launch(void* const* d_in, const int* in_sizes, int n_in,
                              void* d_out, int out_size, void* d_ws, size_t ws_size,
                              hipStream_t stream) {
    const float* x    = (const float*)d_in[0];
    const void*  ei   = d_in[1];
    const void*  batch= d_in[2];
    const float* W1   = (const float*)d_in[3];
    const float* b1   = (const float*)d_in[4];
    const float* W2   = (const float*)d_in[5];
    const float* b2   = (const float*)d_in[6];
    const float* Wmu  = (const float*)d_in[7];
    const float* bmu  = (const float*)d_in[8];
    const float* Wlv  = (const float*)d_in[9];
    const float* blv  = (const float*)d_in[10];
    const float* Wd1  = (const float*)d_in[11];
    const float* bd1  = (const float*)d_in[12];
    const float* Wd2  = (const float*)d_in[13];
    const float* bd2  = (const float*)d_in[14];

    const int N = in_sizes[0] / 64;       // 100000
    const int E = in_sizes[1] / 2;        // 1000000
    const int G = 256;

    float* out = (float*)d_out;

    // workspace layout
    float* dinv = (float*)d_ws;                         // N (deg -> dinv in place)
    float* A    = dinv + ((N + 255) & ~255);            // N*64
    float* B    = A + (size_t)N * 64;                   // N*64
    float* sums = B + (size_t)N * 64;                   // G*64
    float* cnts = sums + (size_t)G * 64;                // G
    int*   flag = (int*)(cnts + G);                     // 1

    const int total = N * 64;
    const int blkN     = (N + 255) / 256;
    const int blkE     = (E + 255) / 256;
    const int blkTotal = (total + 255) / 256;
    const int blkRows  = (N + 3) / 4;
    const int blkEdges = (E + 3) / 4;

    // detect index dtype (int64 reference vs int32 harness-converted)
    detect_idx64<<<1, 256, 0, stream>>>((const unsigned*)ei, E, flag);

    // degrees -> dinv
    deg_init<<<blkN, 256, 0, stream>>>(dinv, N);
    deg_accum<<<blkE, 256, 0, stream>>>(ei, flag, dinv, E);
    deg_to_dinv<<<blkN, 256, 0, stream>>>(dinv, N);

    // conv1: A = x@W1 ; B = selfloop + scatter ; B = relu(B + b1)
    lin64<<<blkRows, 256, 0, stream>>>(x, W1, A, N);
    agg_init<<<blkTotal, 256, 0, stream>>>(A, dinv, B, total);
    gcn_agg_edges<<<blkEdges, 256, 0, stream>>>(A, dinv, ei, flag, B, E);
    agg_finish<<<blkTotal, 256, 0, stream>>>(B, b1, total);

    // conv2: A = B@W2 ; B = selfloop + scatter ; B = relu(B + b2)
    lin64<<<blkRows, 256, 0, stream>>>(B, W2, A, N);
    agg_init<<<blkTotal, 256, 0, stream>>>(A, dinv, B, total);
    gcn_agg_edges<<<blkEdges, 256, 0, stream>>>(A, dinv, ei, flag, B, E);
    agg_finish<<<blkTotal, 256, 0, stream>>>(B, b2, total);

    // pool + head
    pool_init<<<(G * 64 + 255) / 256, 256, 0, stream>>>(sums, cnts, G);
    pool_accum<<<blkRows, 256, 0, stream>>>(B, batch, flag, sums, cnts, N);
    vae_head<<<G, 64, 0, stream>>>(sums, cnts, Wmu, bmu, Wlv, blv,
                                   Wd1, bd1, Wd2, bd2, out);
}

// Round 4
// 718.223 us; speedup vs baseline: 1.5344x; 1.5344x over previous
//
#include <hip/hip_runtime.h>
#include <hip/hip_bf16.h>

// ---------------- JAX threefry2x32 (partitionable) + normal(key=42) --------

__device__ inline unsigned rotl32(unsigned x, unsigned r) {
    return (x << r) | (x >> (32 - r));
}

__device__ inline void threefry2x32_042(unsigned c0, unsigned c1,
                                        unsigned& o0, unsigned& o1) {
    const unsigned k0 = 0u, k1 = 42u;
    unsigned ks[3] = { k0, k1, k0 ^ k1 ^ 0x1BD11BDAu };
    unsigned x0 = c0 + ks[0];
    unsigned x1 = c1 + ks[1];
    const unsigned rotA[4] = {13u, 15u, 26u, 6u};
    const unsigned rotB[4] = {17u, 29u, 16u, 24u};

    #pragma unroll
    for (int i = 0; i < 5; ++i) {
        #pragma unroll
        for (int j = 0; j < 4; ++j) {
            unsigned r = (i & 1) ? rotB[j] : rotA[j];
            x0 += x1;
            x1 = rotl32(x1, r);
            x1 ^= x0;
        }
        x0 += ks[(i + 1) % 3];
        x1 += ks[(i + 2) % 3] + (unsigned)(i + 1);
    }
    o0 = x0; o1 = x1;
}

__device__ inline float erfinv_f32(float x) {
    float w = -log1pf(-x * x);
    float p;
    if (w < 5.0f) {
        w -= 2.5f;
        p = 2.81022636e-08f;
        p = fmaf(p, w, 3.43273939e-07f);
        p = fmaf(p, w, -3.5233877e-06f);
        p = fmaf(p, w, -4.39150654e-06f);
        p = fmaf(p, w, 0.00021858087f);
        p = fmaf(p, w, -0.00125372503f);
        p = fmaf(p, w, -0.00417768164f);
        p = fmaf(p, w, 0.246640727f);
        p = fmaf(p, w, 1.50140941f);
    } else {
        w = sqrtf(w) - 3.0f;
        p = -0.000200214257f;
        p = fmaf(p, w, 0.000100950558f);
        p = fmaf(p, w, 0.00134934322f);
        p = fmaf(p, w, -0.00367342844f);
        p = fmaf(p, w, 0.00573950773f);
        p = fmaf(p, w, -0.0076224613f);
        p = fmaf(p, w, 0.00943887047f);
        p = fmaf(p, w, 1.00167406f);
        p = fmaf(p, w, 2.83297682f);
    }
    return p * x;
}

__device__ inline float jax_normal_4232(unsigned idx) {
    unsigned o0, o1;
    threefry2x32_042(0u, idx, o0, o1);
    unsigned bits = o0 ^ o1;
    unsigned fb = (bits >> 9) | 0x3f800000u;
    float f = __uint_as_float(fb) - 1.0f;              // [0, 1)
    const float lo = -0.99999994f;                     // nextafter(-1, 0)
    float u = f * (1.0f - lo) + lo;
    u = fmaxf(u, lo);
    return 1.41421356f * erfinv_f32(u);
}

// ---------------- int64/int32 index handling -------------------------------

__device__ inline int idx_at(const void* p, long long i, int is64) {
    return is64 ? (int)((const long long*)p)[i] : ((const int*)p)[i];
}

__global__ __launch_bounds__(256) void detect_idx64(const unsigned* __restrict__ raw,
                                                    int ne, int* flag) {
    __shared__ int nz;
    if (threadIdx.x == 0) nz = 0;
    __syncthreads();
    int stride = ne / 2048;
    if (stride < 1) stride = 1;
    for (int k = threadIdx.x; k < 2048; k += 256) {
        long long j = (long long)k * stride;
        if (j < ne && raw[2 * j + 1] != 0u) nz = 1;
    }
    __syncthreads();
    if (threadIdx.x == 0) flag[0] = (nz == 0) ? 1 : 0;
}

// ---------------- graph kernels -------------------------------------------

__global__ __launch_bounds__(256) void deg_init(float* deg, int n) {
    int i = blockIdx.x * 256 + threadIdx.x;
    if (i < n) deg[i] = 1.0f;
}

__global__ __launch_bounds__(256) void deg_accum(const void* __restrict__ ei,
                                                 const int* __restrict__ flag,
                                                 float* deg, int ne) {
    int i = blockIdx.x * 256 + threadIdx.x;
    int is64 = flag[0];
    if (i < ne) {
        int d = idx_at(ei, (long long)ne + i, is64);   // dst row
        atomicAdd(&deg[d], 1.0f);
    }
}

__global__ __launch_bounds__(256) void deg_to_dinv(float* deg, int n) {
    int i = blockIdx.x * 256 + threadIdx.x;
    if (i < n) deg[i] = rsqrtf(deg[i]);
}

// Fused: Xin (optionally relu(Xin+bin)) @ W -> Y; AGG = Y * dinv[row]^2.
// AGG may alias Xin (thread reads/writes only its own element).
__global__ __launch_bounds__(256) void lin64_fused(const float* __restrict__ X,
                                                   const float* __restrict__ bin,
                                                   const float* __restrict__ W,
                                                   const float* __restrict__ dinv,
                                                   float* __restrict__ Y,
                                                   float* __restrict__ AGG, int nrows) {
    __shared__ float sW[64 * 64];
    __shared__ float sX[4][64];
    int t = threadIdx.x;
    for (int i = t; i < 64 * 64; i += 256) sW[i] = W[i];
    int lane = t & 63;
    int w = t >> 6;
    int row = blockIdx.x * 4 + w;
    if (row < nrows) {
        float v = X[(size_t)row * 64 + lane];
        if (bin) v = fmaxf(v + bin[lane], 0.0f);
        sX[w][lane] = v;
    }
    __syncthreads();
    if (row < nrows) {
        float acc = 0.0f;
        #pragma unroll
        for (int k = 0; k < 64; ++k)
            acc = fmaf(sX[w][k], sW[k * 64 + lane], acc);
        Y[(size_t)row * 64 + lane] = acc;
        float di = dinv[row];
        AGG[(size_t)row * 64 + lane] = acc * di * di;
    }
}

// AGG[dst] += Y[src] * dinv[src]*dinv[dst], 64 lanes per edge
__global__ __launch_bounds__(256) void gcn_agg_edges(const float* __restrict__ Y,
                                                     const float* __restrict__ dinv,
                                                     const void* __restrict__ ei,
                                                     const int* __restrict__ flag,
                                                     float* __restrict__ AGG, int ne) {
    int t = threadIdx.x;
    int e = blockIdx.x * 4 + (t >> 6);
    int c = t & 63;
    int is64 = flag[0];
    if (e < ne) {
        int s = idx_at(ei, e, is64);                    // src row
        int d = idx_at(ei, (long long)ne + e, is64);    // dst row
        float norm = dinv[s] * dinv[d];
        atomicAdd(&AGG[(size_t)d * 64 + c], Y[(size_t)s * 64 + c] * norm);
    }
}

__global__ __launch_bounds__(256) void pool_init(float* sums, float* counts, int g) {
    int i = blockIdx.x * 256 + threadIdx.x;
    if (i < g * 64) sums[i] = 0.0f;
    if (i < g) counts[i] = 0.0f;
}

// Segmented pooling over sorted batch: each wave walks a 512-node window
// (stride 4), accumulates relu(X+b) in registers while graph id unchanged,
// flushes one coalesced atomic per (graph, transition).
#define POOL_WIN 512
__global__ __launch_bounds__(256) void pool_seg(const float* __restrict__ X,
                                                const float* __restrict__ b,
                                                const void* __restrict__ batch,
                                                const int* __restrict__ flag,
                                                float* __restrict__ sums,
                                                float* __restrict__ counts, int n) {
    int t = threadIdx.x;
    int c = t & 63;
    int w = t >> 6;
    int base = blockIdx.x * POOL_WIN;
    int is64 = flag[0];
    float bc = b[c];
    float acc = 0.0f, cnt = 0.0f;
    int cur = -1;
    int lim = base + POOL_WIN;
    if (lim > n) lim = n;
    for (int i = base + w; i < lim; i += 4) {
        int g = idx_at(batch, i, is64);
        if (g != cur) {
            if (cur >= 0) {
                atomicAdd(&sums[(size_t)cur * 64 + c], acc);
                if (c == 0) atomicAdd(&counts[cur], cnt);
            }
            cur = g; acc = 0.0f; cnt = 0.0f;
        }
        acc += fmaxf(X[(size_t)i * 64 + c] + bc, 0.0f);
        cnt += 1.0f;
    }
    if (cur >= 0) {
        atomicAdd(&sums[(size_t)cur * 64 + c], acc);
        if (c == 0) atomicAdd(&counts[cur], cnt);
    }
}

// One block (64 threads) per graph: pooled -> mu/logvar -> z -> recon
__global__ __launch_bounds__(64) void vae_head(const float* __restrict__ sums,
                                               const float* __restrict__ counts,
                                               const float* __restrict__ Wmu,
                                               const float* __restrict__ bmu,
                                               const float* __restrict__ Wlv,
                                               const float* __restrict__ blv,
                                               const float* __restrict__ Wd1,
                                               const float* __restrict__ bd1,
                                               const float* __restrict__ Wd2,
                                               const float* __restrict__ bd2,
                                               float* __restrict__ out) {
    int g = blockIdx.x;
    int t = threadIdx.x;  // 64 threads
    __shared__ float sp[64];
    __shared__ float sz[32];
    __shared__ float sh[64];

    float cnt = fmaxf(counts[g], 1.0f);
    sp[t] = sums[(size_t)g * 64 + t] / cnt;
    __syncthreads();

    if (t < 32) {
        float mu = bmu[t];
        float lv = blv[t];
        #pragma unroll
        for (int k = 0; k < 64; ++k) {
            float pk = sp[k];
            mu = fmaf(pk, Wmu[k * 32 + t], mu);
            lv = fmaf(pk, Wlv[k * 32 + t], lv);
        }
        unsigned idx = (unsigned)(g * 32 + t);
        float eps = jax_normal_4232(idx);
        float z = fmaf(eps, expf(0.5f * lv), mu);
        sz[t] = z;
        out[16384 + (size_t)g * 32 + t] = mu;       // mu block
        out[24576 + (size_t)g * 32 + t] = lv;       // logvar block
    }
    __syncthreads();

    float h = bd1[t];
    #pragma unroll
    for (int k = 0; k < 32; ++k) h = fmaf(sz[k], Wd1[k * 64 + t], h);
    h = fmaxf(h, 0.0f);
    sh[t] = h;
    __syncthreads();

    float r = bd2[t];
    #pragma unroll
    for (int k = 0; k < 64; ++k) r = fmaf(sh[k], Wd2[k * 64 + t], r);
    out[(size_t)g * 64 + t] = r;                    // recon block
}

// ---------------- launch ----------------------------------------------------

extern "C" void kernel_launch(void* const* d_in, const int* in_sizes, int n_in,
                              void* d_out, int out_size, void* d_ws, size_t ws_size,
                              hipStream_t stream) {
    const float* x    = (const float*)d_in[0];
    const void*  ei   = d_in[1];
    const void*  batch= d_in[2];
    const float* W1   = (const float*)d_in[3];
    const float* b1   = (const float*)d_in[4];
    const float* W2   = (const float*)d_in[5];
    const float* b2   = (const float*)d_in[6];
    const float* Wmu  = (const float*)d_in[7];
    const float* bmu  = (const float*)d_in[8];
    const float* Wlv  = (const float*)d_in[9];
    const float* blv  = (const float*)d_in[10];
    const float* Wd1  = (const float*)d_in[11];
    const float* bd1  = (const float*)d_in[12];
    const float* Wd2  = (const float*)d_in[13];
    const float* bd2  = (const float*)d_in[14];

    const int N = in_sizes[0] / 64;       // 100000
    const int E = in_sizes[1] / 2;        // 1000000
    const int G = 256;

    float* out = (float*)d_out;

    // workspace layout
    float* dinv = (float*)d_ws;                         // N (deg -> dinv in place)
    float* A    = dinv + ((N + 255) & ~255);            // N*64  (h)
    float* B    = A + (size_t)N * 64;                   // N*64  (agg, pre-bias)
    float* sums = B + (size_t)N * 64;                   // G*64
    float* cnts = sums + (size_t)G * 64;                // G
    int*   flag = (int*)(cnts + G);                     // 1

    const int blkN     = (N + 255) / 256;
    const int blkE     = (E + 255) / 256;
    const int blkRows  = (N + 3) / 4;
    const int blkEdges = (E + 3) / 4;
    const int blkPool  = (N + POOL_WIN - 1) / POOL_WIN;

    // detect index dtype (int64 reference vs int32 harness-converted)
    detect_idx64<<<1, 256, 0, stream>>>((const unsigned*)ei, E, flag);

    // degrees -> dinv
    deg_init<<<blkN, 256, 0, stream>>>(dinv, N);
    deg_accum<<<blkE, 256, 0, stream>>>(ei, flag, dinv, E);
    deg_to_dinv<<<blkN, 256, 0, stream>>>(dinv, N);

    // conv1: A = x@W1 ; B = A*dinv^2 ; scatter into B  (bias deferred)
    lin64_fused<<<blkRows, 256, 0, stream>>>(x, nullptr, W1, dinv, A, B, N);
    gcn_agg_edges<<<blkEdges, 256, 0, stream>>>(A, dinv, ei, flag, B, E);

    // conv2: input relu(B+b1); A = h2 ; B = h2*dinv^2 (in place) ; scatter
    lin64_fused<<<blkRows, 256, 0, stream>>>(B, b1, W2, dinv, A, B, N);
    gcn_agg_edges<<<blkEdges, 256, 0, stream>>>(A, dinv, ei, flag, B, E);

    // pool (applies relu(B+b2)) + head
    pool_init<<<(G * 64 + 255) / 256, 256, 0, stream>>>(sums, cnts, G);
    pool_seg<<<blkPool, 256, 0, stream>>>(B, b2, batch, flag, sums, cnts, N);
    vae_head<<<G, 64, 0, stream>>>(sums, cnts, Wmu, bmu, Wlv, blv,
                                   Wd1, bd1, Wd2, bd2, out);
}

// Round 5
// 489.407 us; speedup vs baseline: 2.2517x; 1.4675x over previous
//
#include <hip/hip_runtime.h>
#include <hip/hip_bf16.h>

// ---------------- JAX threefry2x32 (partitionable) + normal(key=42) --------

__device__ inline unsigned rotl32(unsigned x, unsigned r) {
    return (x << r) | (x >> (32 - r));
}

__device__ inline void threefry2x32_042(unsigned c0, unsigned c1,
                                        unsigned& o0, unsigned& o1) {
    const unsigned k0 = 0u, k1 = 42u;
    unsigned ks[3] = { k0, k1, k0 ^ k1 ^ 0x1BD11BDAu };
    unsigned x0 = c0 + ks[0];
    unsigned x1 = c1 + ks[1];
    const unsigned rotA[4] = {13u, 15u, 26u, 6u};
    const unsigned rotB[4] = {17u, 29u, 16u, 24u};

    #pragma unroll
    for (int i = 0; i < 5; ++i) {
        #pragma unroll
        for (int j = 0; j < 4; ++j) {
            unsigned r = (i & 1) ? rotB[j] : rotA[j];
            x0 += x1;
            x1 = rotl32(x1, r);
            x1 ^= x0;
        }
        x0 += ks[(i + 1) % 3];
        x1 += ks[(i + 2) % 3] + (unsigned)(i + 1);
    }
    o0 = x0; o1 = x1;
}

__device__ inline float erfinv_f32(float x) {
    float w = -log1pf(-x * x);
    float p;
    if (w < 5.0f) {
        w -= 2.5f;
        p = 2.81022636e-08f;
        p = fmaf(p, w, 3.43273939e-07f);
        p = fmaf(p, w, -3.5233877e-06f);
        p = fmaf(p, w, -4.39150654e-06f);
        p = fmaf(p, w, 0.00021858087f);
        p = fmaf(p, w, -0.00125372503f);
        p = fmaf(p, w, -0.00417768164f);
        p = fmaf(p, w, 0.246640727f);
        p = fmaf(p, w, 1.50140941f);
    } else {
        w = sqrtf(w) - 3.0f;
        p = -0.000200214257f;
        p = fmaf(p, w, 0.000100950558f);
        p = fmaf(p, w, 0.00134934322f);
        p = fmaf(p, w, -0.00367342844f);
        p = fmaf(p, w, 0.00573950773f);
        p = fmaf(p, w, -0.0076224613f);
        p = fmaf(p, w, 0.00943887047f);
        p = fmaf(p, w, 1.00167406f);
        p = fmaf(p, w, 2.83297682f);
    }
    return p * x;
}

__device__ inline float jax_normal_4232(unsigned idx) {
    unsigned o0, o1;
    threefry2x32_042(0u, idx, o0, o1);
    unsigned bits = o0 ^ o1;
    unsigned fb = (bits >> 9) | 0x3f800000u;
    float f = __uint_as_float(fb) - 1.0f;              // [0, 1)
    const float lo = -0.99999994f;                     // nextafter(-1, 0)
    float u = f * (1.0f - lo) + lo;
    u = fmaxf(u, lo);
    return 1.41421356f * erfinv_f32(u);
}

// ---------------- int64/int32 index handling -------------------------------

__device__ inline int idx_at(const void* p, long long i, int is64) {
    return is64 ? (int)((const long long*)p)[i] : ((const int*)p)[i];
}

__global__ __launch_bounds__(256) void detect_idx64(const unsigned* __restrict__ raw,
                                                    int ne, int* flag) {
    __shared__ int nz;
    if (threadIdx.x == 0) nz = 0;
    __syncthreads();
    int stride = ne / 2048;
    if (stride < 1) stride = 1;
    for (int k = threadIdx.x; k < 2048; k += 256) {
        long long j = (long long)k * stride;
        if (j < ne && raw[2 * j + 1] != 0u) nz = 1;
    }
    __syncthreads();
    if (threadIdx.x == 0) flag[0] = (nz == 0) ? 1 : 0;
}

// ---------------- CSR construction ----------------------------------------

__global__ __launch_bounds__(256) void zero_ints(int* p, int n) {
    int i = blockIdx.x * 256 + threadIdx.x;
    if (i < n) p[i] = 0;
}

__global__ __launch_bounds__(256) void deg_count(const void* __restrict__ ei,
                                                 const int* __restrict__ flag,
                                                 int* __restrict__ degi, int ne) {
    int i = blockIdx.x * 256 + threadIdx.x;
    int is64 = flag[0];
    if (i < ne) {
        int d = idx_at(ei, (long long)ne + i, is64);   // dst row
        atomicAdd(&degi[d], 1);
    }
}

__global__ __launch_bounds__(256) void dinv_from_deg(const int* __restrict__ degi,
                                                     float* __restrict__ dinv, int n) {
    int i = blockIdx.x * 256 + threadIdx.x;
    if (i < n) dinv[i] = rsqrtf((float)degi[i] + 1.0f);
}

#define SCAN_B 256
// per-block exclusive scan of degi -> rowptr (local), block totals -> partials
__global__ __launch_bounds__(SCAN_B) void scan1(const int* __restrict__ degi,
                                                int* __restrict__ rowptr,
                                                int* __restrict__ partials, int n) {
    __shared__ int s[SCAN_B];
    int i = blockIdx.x * SCAN_B + threadIdx.x;
    int v = (i < n) ? degi[i] : 0;
    s[threadIdx.x] = v;
    __syncthreads();
    for (int off = 1; off < SCAN_B; off <<= 1) {
        int t = (threadIdx.x >= off) ? s[threadIdx.x - off] : 0;
        __syncthreads();
        s[threadIdx.x] += t;
        __syncthreads();
    }
    if (i < n) rowptr[i] = s[threadIdx.x] - v;          // exclusive within block
    if (threadIdx.x == SCAN_B - 1) partials[blockIdx.x] = s[SCAN_B - 1];
}

// single-block exclusive scan of partials (nb <= 1024)
__global__ __launch_bounds__(1024) void scan2(int* __restrict__ partials, int nb) {
    __shared__ int s[1024];
    int v = (threadIdx.x < nb) ? partials[threadIdx.x] : 0;
    s[threadIdx.x] = v;
    __syncthreads();
    for (int off = 1; off < 1024; off <<= 1) {
        int t = (threadIdx.x >= off) ? s[threadIdx.x - off] : 0;
        __syncthreads();
        s[threadIdx.x] += t;
        __syncthreads();
    }
    if (threadIdx.x < nb) partials[threadIdx.x] = s[threadIdx.x] - v;
}

// rowptr[i] += partials[block]; rowptr[n] = e; cursor = rowptr copy
__global__ __launch_bounds__(SCAN_B) void scan3(int* __restrict__ rowptr,
                                                const int* __restrict__ partials,
                                                int* __restrict__ cursor, int n, int e) {
    int i = blockIdx.x * SCAN_B + threadIdx.x;
    if (i < n) {
        int r = rowptr[i] + partials[blockIdx.x];
        rowptr[i] = r;
        cursor[i] = r;
    }
    if (i == 0) rowptr[n] = e;
}

__global__ __launch_bounds__(256) void csr_fill(const void* __restrict__ ei,
                                                const int* __restrict__ flag,
                                                int* __restrict__ cursor,
                                                int* __restrict__ csr_src, int ne) {
    int i = blockIdx.x * 256 + threadIdx.x;
    int is64 = flag[0];
    if (i < ne) {
        int s = idx_at(ei, i, is64);
        int d = idx_at(ei, (long long)ne + i, is64);
        int slot = atomicAdd(&cursor[d], 1);
        csr_src[slot] = s;
    }
}

// ---------------- compute kernels -----------------------------------------

// Y[n][64] = (optionally relu(X+bin)) @ W[64][64]
__global__ __launch_bounds__(256) void lin64(const float* __restrict__ X,
                                             const float* __restrict__ bin,
                                             const float* __restrict__ W,
                                             float* __restrict__ Y, int nrows) {
    __shared__ float sW[64 * 64];
    __shared__ float sX[4][64];
    int t = threadIdx.x;
    for (int i = t; i < 64 * 64; i += 256) sW[i] = W[i];
    int lane = t & 63;
    int w = t >> 6;
    int row = blockIdx.x * 4 + w;
    if (row < nrows) {
        float v = X[(size_t)row * 64 + lane];
        if (bin) v = fmaxf(v + bin[lane], 0.0f);
        sX[w][lane] = v;
    }
    __syncthreads();
    if (row < nrows) {
        float acc = 0.0f;
        #pragma unroll
        for (int k = 0; k < 64; ++k)
            acc = fmaf(sX[w][k], sW[k * 64 + lane], acc);
        Y[(size_t)row * 64 + lane] = acc;
    }
}

// B[d] = Y[d]*dinv[d]^2 + sum_{e in CSR row d} Y[src]*dinv[src]*dinv[d]
// one wave (64 lanes) per dst node, 4 nodes per block
__global__ __launch_bounds__(256) void gcn_gather(const float* __restrict__ Y,
                                                  const float* __restrict__ dinv,
                                                  const int* __restrict__ rowptr,
                                                  const int* __restrict__ csr_src,
                                                  float* __restrict__ B, int n) {
    int t = threadIdx.x;
    int node = blockIdx.x * 4 + (t >> 6);
    int c = t & 63;
    if (node < n) {
        float dd = dinv[node];
        float acc = Y[(size_t)node * 64 + c] * dd * dd;
        int beg = rowptr[node], end = rowptr[node + 1];
        for (int k = beg; k < end; ++k) {
            int s = csr_src[k];
            float ns = dinv[s] * dd;
            acc = fmaf(Y[(size_t)s * 64 + c], ns, acc);
        }
        B[(size_t)node * 64 + c] = acc;
    }
}

__global__ __launch_bounds__(256) void pool_init(float* sums, float* counts, int g) {
    int i = blockIdx.x * 256 + threadIdx.x;
    if (i < g * 64) sums[i] = 0.0f;
    if (i < g) counts[i] = 0.0f;
}

// Segmented pooling over sorted batch (relu(X+b) applied on the fly)
#define POOL_WIN 512
__global__ __launch_bounds__(256) void pool_seg(const float* __restrict__ X,
                                                const float* __restrict__ b,
                                                const void* __restrict__ batch,
                                                const int* __restrict__ flag,
                                                float* __restrict__ sums,
                                                float* __restrict__ counts, int n) {
    int t = threadIdx.x;
    int c = t & 63;
    int w = t >> 6;
    int base = blockIdx.x * POOL_WIN;
    int is64 = flag[0];
    float bc = b[c];
    float acc = 0.0f, cnt = 0.0f;
    int cur = -1;
    int lim = base + POOL_WIN;
    if (lim > n) lim = n;
    for (int i = base + w; i < lim; i += 4) {
        int g = idx_at(batch, i, is64);
        if (g != cur) {
            if (cur >= 0) {
                atomicAdd(&sums[(size_t)cur * 64 + c], acc);
                if (c == 0) atomicAdd(&counts[cur], cnt);
            }
            cur = g; acc = 0.0f; cnt = 0.0f;
        }
        acc += fmaxf(X[(size_t)i * 64 + c] + bc, 0.0f);
        cnt += 1.0f;
    }
    if (cur >= 0) {
        atomicAdd(&sums[(size_t)cur * 64 + c], acc);
        if (c == 0) atomicAdd(&counts[cur], cnt);
    }
}

// One block (64 threads) per graph: pooled -> mu/logvar -> z -> recon
__global__ __launch_bounds__(64) void vae_head(const float* __restrict__ sums,
                                               const float* __restrict__ counts,
                                               const float* __restrict__ Wmu,
                                               const float* __restrict__ bmu,
                                               const float* __restrict__ Wlv,
                                               const float* __restrict__ blv,
                                               const float* __restrict__ Wd1,
                                               const float* __restrict__ bd1,
                                               const float* __restrict__ Wd2,
                                               const float* __restrict__ bd2,
                                               float* __restrict__ out) {
    int g = blockIdx.x;
    int t = threadIdx.x;  // 64 threads
    __shared__ float sp[64];
    __shared__ float sz[32];
    __shared__ float sh[64];

    float cnt = fmaxf(counts[g], 1.0f);
    sp[t] = sums[(size_t)g * 64 + t] / cnt;
    __syncthreads();

    if (t < 32) {
        float mu = bmu[t];
        float lv = blv[t];
        #pragma unroll
        for (int k = 0; k < 64; ++k) {
            float pk = sp[k];
            mu = fmaf(pk, Wmu[k * 32 + t], mu);
            lv = fmaf(pk, Wlv[k * 32 + t], lv);
        }
        unsigned idx = (unsigned)(g * 32 + t);
        float eps = jax_normal_4232(idx);
        float z = fmaf(eps, expf(0.5f * lv), mu);
        sz[t] = z;
        out[16384 + (size_t)g * 32 + t] = mu;       // mu block
        out[24576 + (size_t)g * 32 + t] = lv;       // logvar block
    }
    __syncthreads();

    float h = bd1[t];
    #pragma unroll
    for (int k = 0; k < 32; ++k) h = fmaf(sz[k], Wd1[k * 64 + t], h);
    h = fmaxf(h, 0.0f);
    sh[t] = h;
    __syncthreads();

    float r = bd2[t];
    #pragma unroll
    for (int k = 0; k < 64; ++k) r = fmaf(sh[k], Wd2[k * 64 + t], r);
    out[(size_t)g * 64 + t] = r;                    // recon block
}

// ---------------- launch ----------------------------------------------------

extern "C" void kernel_launch(void* const* d_in, const int* in_sizes, int n_in,
                              void* d_out, int out_size, void* d_ws, size_t ws_size,
                              hipStream_t stream) {
    const float* x    = (const float*)d_in[0];
    const void*  ei   = d_in[1];
    const void*  batch= d_in[2];
    const float* W1   = (const float*)d_in[3];
    const float* b1   = (const float*)d_in[4];
    const float* W2   = (const float*)d_in[5];
    const float* b2   = (const float*)d_in[6];
    const float* Wmu  = (const float*)d_in[7];
    const float* bmu  = (const float*)d_in[8];
    const float* Wlv  = (const float*)d_in[9];
    const float* blv  = (const float*)d_in[10];
    const float* Wd1  = (const float*)d_in[11];
    const float* bd1  = (const float*)d_in[12];
    const float* Wd2  = (const float*)d_in[13];
    const float* bd2  = (const float*)d_in[14];

    const int N = in_sizes[0] / 64;       // 100000
    const int E = in_sizes[1] / 2;        // 1000000
    const int G = 256;

    float* out = (float*)d_out;

    // workspace layout (floats then ints)
    float* dinv = (float*)d_ws;                         // Npad
    float* A    = dinv + ((N + 255) & ~255);            // N*64  (h)
    float* B    = A + (size_t)N * 64;                   // N*64  (agg, pre-bias)
    float* sums = B + (size_t)N * 64;                   // G*64
    float* cnts = sums + (size_t)G * 64;                // G
    int*   flag = (int*)(cnts + G);                     // 1 (+pad to 256)
    int*   degi = flag + 256;                           // N
    int*   rowptr = degi + N;                           // N+1
    int*   cursor = rowptr + (N + 1);                   // N
    int*   partials = cursor + N;                       // <=1024
    int*   csr_src = partials + 1024;                   // E

    const int blkN     = (N + 255) / 256;
    const int blkE     = (E + 255) / 256;
    const int blkRows  = (N + 3) / 4;
    const int blkPool  = (N + POOL_WIN - 1) / POOL_WIN;
    const int nbScan   = (N + SCAN_B - 1) / SCAN_B;     // 391 <= 1024

    // index dtype detection
    detect_idx64<<<1, 256, 0, stream>>>((const unsigned*)ei, E, flag);

    // CSR build: degree -> dinv, exclusive scan -> rowptr/cursor, fill
    zero_ints<<<blkN, 256, 0, stream>>>(degi, N);
    deg_count<<<blkE, 256, 0, stream>>>(ei, flag, degi, E);
    dinv_from_deg<<<blkN, 256, 0, stream>>>(degi, dinv, N);
    scan1<<<nbScan, SCAN_B, 0, stream>>>(degi, rowptr, partials, N);
    scan2<<<1, 1024, 0, stream>>>(partials, nbScan);
    scan3<<<nbScan, SCAN_B, 0, stream>>>(rowptr, partials, cursor, N, E);
    csr_fill<<<blkE, 256, 0, stream>>>(ei, flag, cursor, csr_src, E);

    // conv1: A = x@W1 ; B = gather(A)
    lin64<<<blkRows, 256, 0, stream>>>(x, nullptr, W1, A, N);
    gcn_gather<<<blkRows, 256, 0, stream>>>(A, dinv, rowptr, csr_src, B, N);

    // conv2: A = relu(B+b1)@W2 ; B = gather(A)
    lin64<<<blkRows, 256, 0, stream>>>(B, b1, W2, A, N);
    gcn_gather<<<blkRows, 256, 0, stream>>>(A, dinv, rowptr, csr_src, B, N);

    // pool (applies relu(B+b2)) + head
    pool_init<<<(G * 64 + 255) / 256, 256, 0, stream>>>(sums, cnts, G);
    pool_seg<<<blkPool, 256, 0, stream>>>(B, b2, batch, flag, sums, cnts, N);
    vae_head<<<G, 64, 0, stream>>>(sums, cnts, Wmu, bmu, Wlv, blv,
                                   Wd1, bd1, Wd2, bd2, out);
}

// Round 6
// 434.709 us; speedup vs baseline: 2.5351x; 1.1258x over previous
//
#include <hip/hip_runtime.h>
#include <hip/hip_bf16.h>

// ---------------- JAX threefry2x32 (partitionable) + normal(key=42) --------

__device__ inline unsigned rotl32(unsigned x, unsigned r) {
    return (x << r) | (x >> (32 - r));
}

__device__ inline void threefry2x32_042(unsigned c0, unsigned c1,
                                        unsigned& o0, unsigned& o1) {
    const unsigned k0 = 0u, k1 = 42u;
    unsigned ks[3] = { k0, k1, k0 ^ k1 ^ 0x1BD11BDAu };
    unsigned x0 = c0 + ks[0];
    unsigned x1 = c1 + ks[1];
    const unsigned rotA[4] = {13u, 15u, 26u, 6u};
    const unsigned rotB[4] = {17u, 29u, 16u, 24u};

    #pragma unroll
    for (int i = 0; i < 5; ++i) {
        #pragma unroll
        for (int j = 0; j < 4; ++j) {
            unsigned r = (i & 1) ? rotB[j] : rotA[j];
            x0 += x1;
            x1 = rotl32(x1, r);
            x1 ^= x0;
        }
        x0 += ks[(i + 1) % 3];
        x1 += ks[(i + 2) % 3] + (unsigned)(i + 1);
    }
    o0 = x0; o1 = x1;
}

__device__ inline float erfinv_f32(float x) {
    float w = -log1pf(-x * x);
    float p;
    if (w < 5.0f) {
        w -= 2.5f;
        p = 2.81022636e-08f;
        p = fmaf(p, w, 3.43273939e-07f);
        p = fmaf(p, w, -3.5233877e-06f);
        p = fmaf(p, w, -4.39150654e-06f);
        p = fmaf(p, w, 0.00021858087f);
        p = fmaf(p, w, -0.00125372503f);
        p = fmaf(p, w, -0.00417768164f);
        p = fmaf(p, w, 0.246640727f);
        p = fmaf(p, w, 1.50140941f);
    } else {
        w = sqrtf(w) - 3.0f;
        p = -0.000200214257f;
        p = fmaf(p, w, 0.000100950558f);
        p = fmaf(p, w, 0.00134934322f);
        p = fmaf(p, w, -0.00367342844f);
        p = fmaf(p, w, 0.00573950773f);
        p = fmaf(p, w, -0.0076224613f);
        p = fmaf(p, w, 0.00943887047f);
        p = fmaf(p, w, 1.00167406f);
        p = fmaf(p, w, 2.83297682f);
    }
    return p * x;
}

__device__ inline float jax_normal_4232(unsigned idx) {
    unsigned o0, o1;
    threefry2x32_042(0u, idx, o0, o1);
    unsigned bits = o0 ^ o1;
    unsigned fb = (bits >> 9) | 0x3f800000u;
    float f = __uint_as_float(fb) - 1.0f;              // [0, 1)
    const float lo = -0.99999994f;                     // nextafter(-1, 0)
    float u = f * (1.0f - lo) + lo;
    u = fmaxf(u, lo);
    return 1.41421356f * erfinv_f32(u);
}

// ---------------- int64/int32 index handling -------------------------------

__device__ inline int idx_at(const void* p, long long i, int is64) {
    return is64 ? (int)((const long long*)p)[i] : ((const int*)p)[i];
}

__global__ __launch_bounds__(256) void detect_idx64(const unsigned* __restrict__ raw,
                                                    int ne, int* flag) {
    __shared__ int nz;
    if (threadIdx.x == 0) nz = 0;
    __syncthreads();
    int stride = ne / 2048;
    if (stride < 1) stride = 1;
    for (int k = threadIdx.x; k < 2048; k += 256) {
        long long j = (long long)k * stride;
        if (j < ne && raw[2 * j + 1] != 0u) nz = 1;
    }
    __syncthreads();
    if (threadIdx.x == 0) flag[0] = (nz == 0) ? 1 : 0;
}

// ---------------- CSR construction ----------------------------------------

__global__ __launch_bounds__(256) void deg_count(const void* __restrict__ ei,
                                                 const int* __restrict__ flag,
                                                 int* __restrict__ degi, int ne) {
    int i = blockIdx.x * 256 + threadIdx.x;
    int is64 = flag[0];
    if (i < ne) {
        int d = idx_at(ei, (long long)ne + i, is64);   // dst row
        atomicAdd(&degi[d], 1);
    }
}

#define SCAN_B 256
// per-block exclusive scan of degi -> rowptr (local), block totals -> partials
// also emits dinv = rsqrt(deg+1)
__global__ __launch_bounds__(SCAN_B) void scan1(const int* __restrict__ degi,
                                                int* __restrict__ rowptr,
                                                int* __restrict__ partials,
                                                float* __restrict__ dinv, int n) {
    __shared__ int s[SCAN_B];
    int i = blockIdx.x * SCAN_B + threadIdx.x;
    int v = (i < n) ? degi[i] : 0;
    s[threadIdx.x] = v;
    __syncthreads();
    for (int off = 1; off < SCAN_B; off <<= 1) {
        int t = (threadIdx.x >= off) ? s[threadIdx.x - off] : 0;
        __syncthreads();
        s[threadIdx.x] += t;
        __syncthreads();
    }
    if (i < n) {
        rowptr[i] = s[threadIdx.x] - v;                 // exclusive within block
        dinv[i] = rsqrtf((float)v + 1.0f);
    }
    if (threadIdx.x == SCAN_B - 1) partials[blockIdx.x] = s[SCAN_B - 1];
}

// single-block exclusive scan of partials (nb <= 1024)
__global__ __launch_bounds__(1024) void scan2(int* __restrict__ partials, int nb) {
    __shared__ int s[1024];
    int v = (threadIdx.x < nb) ? partials[threadIdx.x] : 0;
    s[threadIdx.x] = v;
    __syncthreads();
    for (int off = 1; off < 1024; off <<= 1) {
        int t = (threadIdx.x >= off) ? s[threadIdx.x - off] : 0;
        __syncthreads();
        s[threadIdx.x] += t;
        __syncthreads();
    }
    if (threadIdx.x < nb) partials[threadIdx.x] = s[threadIdx.x] - v;
}

// rowptr[i] += partials[block]; rowptr[n] = e; cursor = rowptr copy
__global__ __launch_bounds__(SCAN_B) void scan3(int* __restrict__ rowptr,
                                                const int* __restrict__ partials,
                                                int* __restrict__ cursor, int n, int e) {
    int i = blockIdx.x * SCAN_B + threadIdx.x;
    if (i < n) {
        int r = rowptr[i] + partials[blockIdx.x];
        rowptr[i] = r;
        cursor[i] = r;
    }
    if (i == 0) rowptr[n] = e;
}

__global__ __launch_bounds__(256) void csr_fill(const void* __restrict__ ei,
                                                const int* __restrict__ flag,
                                                int* __restrict__ cursor,
                                                int* __restrict__ csr_src, int ne) {
    int i = blockIdx.x * 256 + threadIdx.x;
    int is64 = flag[0];
    if (i < ne) {
        int s = idx_at(ei, i, is64);
        int d = idx_at(ei, (long long)ne + i, is64);
        int slot = atomicAdd(&cursor[d], 1);
        csr_src[slot] = s;
    }
}

// ---------------- compute kernels -----------------------------------------

// A[row][c] = bf16( ((optionally relu(X+bin)) @ W)[row][c] * dinv[row] )
__global__ __launch_bounds__(256) void lin64_bf16(const float* __restrict__ X,
                                                  const float* __restrict__ bin,
                                                  const float* __restrict__ W,
                                                  const float* __restrict__ dinv,
                                                  __hip_bfloat16* __restrict__ Y,
                                                  int nrows) {
    __shared__ float sW[64 * 64];
    __shared__ float sX[4][64];
    int t = threadIdx.x;
    for (int i = t; i < 64 * 64; i += 256) sW[i] = W[i];
    int lane = t & 63;
    int w = t >> 6;
    int row = blockIdx.x * 4 + w;
    if (row < nrows) {
        float v = X[(size_t)row * 64 + lane];
        if (bin) v = fmaxf(v + bin[lane], 0.0f);
        sX[w][lane] = v;
    }
    __syncthreads();
    if (row < nrows) {
        float acc = 0.0f;
        #pragma unroll
        for (int k = 0; k < 64; ++k)
            acc = fmaf(sX[w][k], sW[k * 64 + lane], acc);
        Y[(size_t)row * 64 + lane] = __float2bfloat16(acc * dinv[row]);
    }
}

// B[d][c] = dinv[d] * ( A[d][c] + sum_{s in CSR row d} A[s][c] )
// one wave (64 lanes) per dst node; csr row loaded cooperatively + shfl-broadcast
__global__ __launch_bounds__(256) void gcn_gather(const __hip_bfloat16* __restrict__ A,
                                                  const float* __restrict__ dinv,
                                                  const int* __restrict__ rowptr,
                                                  const int* __restrict__ csr_src,
                                                  float* __restrict__ B, int n) {
    int t = threadIdx.x;
    int node = blockIdx.x * 4 + (t >> 6);
    int c = t & 63;
    if (node >= n) return;
    float acc = __bfloat162float(A[(size_t)node * 64 + c]);   // self loop
    int beg = rowptr[node], end = rowptr[node + 1];
    for (int chunk = beg; chunk < end; chunk += 64) {
        int m = end - chunk;
        if (m > 64) m = 64;
        int sl = (c < m) ? csr_src[chunk + c] : 0;            // coalesced
        for (int j = 0; j < m; ++j) {
            int s = __shfl(sl, j);
            acc += __bfloat162float(A[(size_t)s * 64 + c]);
        }
    }
    B[(size_t)node * 64 + c] = acc * dinv[node];
}

// Segmented pooling over sorted batch (relu(X+b) applied on the fly)
#define POOL_WIN 512
__global__ __launch_bounds__(256) void pool_seg(const float* __restrict__ X,
                                                const float* __restrict__ b,
                                                const void* __restrict__ batch,
                                                const int* __restrict__ flag,
                                                float* __restrict__ sums,
                                                float* __restrict__ counts, int n) {
    int t = threadIdx.x;
    int c = t & 63;
    int w = t >> 6;
    int base = blockIdx.x * POOL_WIN;
    int is64 = flag[0];
    float bc = b[c];
    float acc = 0.0f, cnt = 0.0f;
    int cur = -1;
    int lim = base + POOL_WIN;
    if (lim > n) lim = n;
    for (int i = base + w; i < lim; i += 4) {
        int g = idx_at(batch, i, is64);
        if (g != cur) {
            if (cur >= 0) {
                atomicAdd(&sums[(size_t)cur * 64 + c], acc);
                if (c == 0) atomicAdd(&counts[cur], cnt);
            }
            cur = g; acc = 0.0f; cnt = 0.0f;
        }
        acc += fmaxf(X[(size_t)i * 64 + c] + bc, 0.0f);
        cnt += 1.0f;
    }
    if (cur >= 0) {
        atomicAdd(&sums[(size_t)cur * 64 + c], acc);
        if (c == 0) atomicAdd(&counts[cur], cnt);
    }
}

// One block (64 threads) per graph: pooled -> mu/logvar -> z -> recon
__global__ __launch_bounds__(64) void vae_head(const float* __restrict__ sums,
                                               const float* __restrict__ counts,
                                               const float* __restrict__ Wmu,
                                               const float* __restrict__ bmu,
                                               const float* __restrict__ Wlv,
                                               const float* __restrict__ blv,
                                               const float* __restrict__ Wd1,
                                               const float* __restrict__ bd1,
                                               const float* __restrict__ Wd2,
                                               const float* __restrict__ bd2,
                                               float* __restrict__ out) {
    int g = blockIdx.x;
    int t = threadIdx.x;  // 64 threads
    __shared__ float sp[64];
    __shared__ float sz[32];
    __shared__ float sh[64];

    float cnt = fmaxf(counts[g], 1.0f);
    sp[t] = sums[(size_t)g * 64 + t] / cnt;
    __syncthreads();

    if (t < 32) {
        float mu = bmu[t];
        float lv = blv[t];
        #pragma unroll
        for (int k = 0; k < 64; ++k) {
            float pk = sp[k];
            mu = fmaf(pk, Wmu[k * 32 + t], mu);
            lv = fmaf(pk, Wlv[k * 32 + t], lv);
        }
        unsigned idx = (unsigned)(g * 32 + t);
        float eps = jax_normal_4232(idx);
        float z = fmaf(eps, expf(0.5f * lv), mu);
        sz[t] = z;
        out[16384 + (size_t)g * 32 + t] = mu;       // mu block
        out[24576 + (size_t)g * 32 + t] = lv;       // logvar block
    }
    __syncthreads();

    float h = bd1[t];
    #pragma unroll
    for (int k = 0; k < 32; ++k) h = fmaf(sz[k], Wd1[k * 64 + t], h);
    h = fmaxf(h, 0.0f);
    sh[t] = h;
    __syncthreads();

    float r = bd2[t];
    #pragma unroll
    for (int k = 0; k < 64; ++k) r = fmaf(sh[k], Wd2[k * 64 + t], r);
    out[(size_t)g * 64 + t] = r;                    // recon block
}

// ---------------- launch ----------------------------------------------------

extern "C" void kernel_launch(void* const* d_in, const int* in_sizes, int n_in,
                              void* d_out, int out_size, void* d_ws, size_t ws_size,
                              hipStream_t stream) {
    const float* x    = (const float*)d_in[0];
    const void*  ei   = d_in[1];
    const void*  batch= d_in[2];
    const float* W1   = (const float*)d_in[3];
    const float* b1   = (const float*)d_in[4];
    const float* W2   = (const float*)d_in[5];
    const float* b2   = (const float*)d_in[6];
    const float* Wmu  = (const float*)d_in[7];
    const float* bmu  = (const float*)d_in[8];
    const float* Wlv  = (const float*)d_in[9];
    const float* blv  = (const float*)d_in[10];
    const float* Wd1  = (const float*)d_in[11];
    const float* bd1  = (const float*)d_in[12];
    const float* Wd2  = (const float*)d_in[13];
    const float* bd2  = (const float*)d_in[14];

    const int N = in_sizes[0] / 64;       // 100000
    const int E = in_sizes[1] / 2;        // 1000000
    const int G = 256;

    float* out = (float*)d_out;

    // workspace layout
    float* dinv = (float*)d_ws;                          // Npad floats
    __hip_bfloat16* A = (__hip_bfloat16*)(dinv + ((N + 255) & ~255)); // N*64 bf16
    float* B    = (float*)(A + (size_t)N * 64);          // N*64 fp32
    float* sums = B + (size_t)N * 64;                    // G*64
    float* cnts = sums + (size_t)G * 64;                 // G   (contiguous w/ sums)
    int*   flag = (int*)(cnts + G);                      // 1 (+pad)
    int*   degi = flag + 256;                            // N
    int*   rowptr = degi + N;                            // N+1
    int*   cursor = rowptr + (N + 1);                    // N
    int*   partials = cursor + N;                        // <=1024
    int*   csr_src = partials + 1024;                    // E

    const int blkE     = (E + 255) / 256;
    const int blkRows  = (N + 3) / 4;
    const int blkPool  = (N + POOL_WIN - 1) / POOL_WIN;
    const int nbScan   = (N + SCAN_B - 1) / SCAN_B;      // 391 <= 1024

    // index dtype detection
    detect_idx64<<<1, 256, 0, stream>>>((const unsigned*)ei, E, flag);

    // CSR build: degree -> (rowptr scan + dinv), fill
    hipMemsetAsync(degi, 0, (size_t)N * sizeof(int), stream);
    deg_count<<<blkE, 256, 0, stream>>>(ei, flag, degi, E);
    scan1<<<nbScan, SCAN_B, 0, stream>>>(degi, rowptr, partials, dinv, N);
    scan2<<<1, 1024, 0, stream>>>(partials, nbScan);
    scan3<<<nbScan, SCAN_B, 0, stream>>>(rowptr, partials, cursor, N, E);
    csr_fill<<<blkE, 256, 0, stream>>>(ei, flag, cursor, csr_src, E);

    // conv1: A = bf16(x@W1 * dinv) ; B = gather(A) * dinv
    lin64_bf16<<<blkRows, 256, 0, stream>>>(x, nullptr, W1, dinv, A, N);
    gcn_gather<<<blkRows, 256, 0, stream>>>(A, dinv, rowptr, csr_src, B, N);

    // conv2: A = bf16(relu(B+b1)@W2 * dinv) ; B = gather(A) * dinv
    lin64_bf16<<<blkRows, 256, 0, stream>>>(B, b1, W2, dinv, A, N);
    gcn_gather<<<blkRows, 256, 0, stream>>>(A, dinv, rowptr, csr_src, B, N);

    // pool (applies relu(B+b2)) + head
    hipMemsetAsync(sums, 0, (size_t)(G * 64 + G) * sizeof(float), stream);
    pool_seg<<<blkPool, 256, 0, stream>>>(B, b2, batch, flag, sums, cnts, N);
    vae_head<<<G, 64, 0, stream>>>(sums, cnts, Wmu, bmu, Wlv, blv,
                                   Wd1, bd1, Wd2, bd2, out);
}

// Round 7
// 305.493 us; speedup vs baseline: 3.6073x; 1.4230x over previous
//
#include <hip/hip_runtime.h>
#include <hip/hip_bf16.h>

// ---------------- JAX threefry2x32 (partitionable) + normal(key=42) --------

__device__ inline unsigned rotl32(unsigned x, unsigned r) {
    return (x << r) | (x >> (32 - r));
}

__device__ inline void threefry2x32_042(unsigned c0, unsigned c1,
                                        unsigned& o0, unsigned& o1) {
    const unsigned k0 = 0u, k1 = 42u;
    unsigned ks[3] = { k0, k1, k0 ^ k1 ^ 0x1BD11BDAu };
    unsigned x0 = c0 + ks[0];
    unsigned x1 = c1 + ks[1];
    const unsigned rotA[4] = {13u, 15u, 26u, 6u};
    const unsigned rotB[4] = {17u, 29u, 16u, 24u};

    #pragma unroll
    for (int i = 0; i < 5; ++i) {
        #pragma unroll
        for (int j = 0; j < 4; ++j) {
            unsigned r = (i & 1) ? rotB[j] : rotA[j];
            x0 += x1;
            x1 = rotl32(x1, r);
            x1 ^= x0;
        }
        x0 += ks[(i + 1) % 3];
        x1 += ks[(i + 2) % 3] + (unsigned)(i + 1);
    }
    o0 = x0; o1 = x1;
}

__device__ inline float erfinv_f32(float x) {
    float w = -log1pf(-x * x);
    float p;
    if (w < 5.0f) {
        w -= 2.5f;
        p = 2.81022636e-08f;
        p = fmaf(p, w, 3.43273939e-07f);
        p = fmaf(p, w, -3.5233877e-06f);
        p = fmaf(p, w, -4.39150654e-06f);
        p = fmaf(p, w, 0.00021858087f);
        p = fmaf(p, w, -0.00125372503f);
        p = fmaf(p, w, -0.00417768164f);
        p = fmaf(p, w, 0.246640727f);
        p = fmaf(p, w, 1.50140941f);
    } else {
        w = sqrtf(w) - 3.0f;
        p = -0.000200214257f;
        p = fmaf(p, w, 0.000100950558f);
        p = fmaf(p, w, 0.00134934322f);
        p = fmaf(p, w, -0.00367342844f);
        p = fmaf(p, w, 0.00573950773f);
        p = fmaf(p, w, -0.0076224613f);
        p = fmaf(p, w, 0.00943887047f);
        p = fmaf(p, w, 1.00167406f);
        p = fmaf(p, w, 2.83297682f);
    }
    return p * x;
}

__device__ inline float jax_normal_4232(unsigned idx) {
    unsigned o0, o1;
    threefry2x32_042(0u, idx, o0, o1);
    unsigned bits = o0 ^ o1;
    unsigned fb = (bits >> 9) | 0x3f800000u;
    float f = __uint_as_float(fb) - 1.0f;              // [0, 1)
    const float lo = -0.99999994f;                     // nextafter(-1, 0)
    float u = f * (1.0f - lo) + lo;
    u = fmaxf(u, lo);
    return 1.41421356f * erfinv_f32(u);
}

// ---------------- int64/int32 index handling -------------------------------

__device__ inline int idx_at(const void* p, long long i, int is64) {
    return is64 ? (int)((const long long*)p)[i] : ((const int*)p)[i];
}

__global__ __launch_bounds__(256) void detect_idx64(const unsigned* __restrict__ raw,
                                                    int ne, int* flag) {
    __shared__ int nz;
    if (threadIdx.x == 0) nz = 0;
    __syncthreads();
    int stride = ne / 2048;
    if (stride < 1) stride = 1;
    for (int k = threadIdx.x; k < 2048; k += 256) {
        long long j = (long long)k * stride;
        if (j < ne && raw[2 * j + 1] != 0u) nz = 1;
    }
    __syncthreads();
    if (threadIdx.x == 0) flag[0] = (nz == 0) ? 1 : 0;
}

// ---------------- bucketed CSR construction --------------------------------
// Buckets = contiguous dst-node ranges of NPB nodes; nbu = ceil(N/NPB) <= 256.

#define NBK 256

// per-block LDS histogram of edge dst-buckets -> global bcnt
__global__ __launch_bounds__(256) void bucket_count(const void* __restrict__ ei,
                                                    const int* __restrict__ flag,
                                                    int* __restrict__ bcnt,
                                                    int ne, int npb, int chunk) {
    __shared__ int hist[NBK];
    int t = threadIdx.x;
    hist[t] = 0;
    __syncthreads();
    int is64 = flag[0];
    int c0 = blockIdx.x * chunk;
    int c1 = c0 + chunk; if (c1 > ne) c1 = ne;
    for (int i = c0 + t; i < c1; i += 256) {
        int d = idx_at(ei, (long long)ne + i, is64);
        atomicAdd(&hist[d / npb], 1);
    }
    __syncthreads();
    if (hist[t] > 0) atomicAdd(&bcnt[t], hist[t]);
}

// single-block exclusive scan of bucket counts -> ebase (+sentinel), gcursor
__global__ __launch_bounds__(256) void bucket_scan(const int* __restrict__ bcnt,
                                                   int* __restrict__ ebase,
                                                   int* __restrict__ gcur,
                                                   int nbu, int ne) {
    __shared__ int s[NBK];
    int t = threadIdx.x;
    int v = (t < nbu) ? bcnt[t] : 0;
    s[t] = v;
    __syncthreads();
    for (int off = 1; off < NBK; off <<= 1) {
        int tmp = (t >= off) ? s[t - off] : 0;
        __syncthreads();
        s[t] += tmp;
        __syncthreads();
    }
    int excl = s[t] - v;
    if (t < nbu) { ebase[t] = excl; gcur[t] = excl; }
    if (t == 0) ebase[nbu] = ne;
}

// partition edges into bucket regions of `pairs` (contiguous reservations)
__global__ __launch_bounds__(256) void bucket_fill(const void* __restrict__ ei,
                                                   const int* __restrict__ flag,
                                                   int* __restrict__ gcur,
                                                   int2* __restrict__ pairs,
                                                   int ne, int npb, int chunk) {
    __shared__ int hist[NBK];
    __shared__ int basecur[NBK];
    int t = threadIdx.x;
    hist[t] = 0;
    __syncthreads();
    int is64 = flag[0];
    int c0 = blockIdx.x * chunk;
    int c1 = c0 + chunk; if (c1 > ne) c1 = ne;
    for (int i = c0 + t; i < c1; i += 256) {
        int d = idx_at(ei, (long long)ne + i, is64);
        atomicAdd(&hist[d / npb], 1);
    }
    __syncthreads();
    if (hist[t] > 0) basecur[t] = atomicAdd(&gcur[t], hist[t]);
    __syncthreads();
    for (int i = c0 + t; i < c1; i += 256) {
        int s = idx_at(ei, i, is64);
        int d = idx_at(ei, (long long)ne + i, is64);
        int slot = atomicAdd(&basecur[d / npb], 1);
        pairs[slot] = make_int2(s, d);
    }
}

// one block per bucket: per-node degree (LDS) -> wave scan -> rowptr/dinv,
// then LDS-cursor fill of csr_src (contiguous region per bucket)
#define NPB_MAX 512
__global__ __launch_bounds__(256) void csr_build(const int2* __restrict__ pairs,
                                                 const int* __restrict__ ebase,
                                                 int* __restrict__ rowptr,
                                                 float* __restrict__ dinv,
                                                 int* __restrict__ csr_src,
                                                 int n, int ne, int npb) {
    __shared__ int cnt[NPB_MAX];
    __shared__ int cur[NPB_MAX];
    int b = blockIdx.x;
    int t = threadIdx.x;
    int bstart = b * npb;
    int bn = n - bstart; if (bn > npb) bn = npb;
    int e0 = ebase[b], e1 = ebase[b + 1];

    for (int i = t; i < bn; i += 256) cnt[i] = 0;
    __syncthreads();
    for (int i = e0 + t; i < e1; i += 256)
        atomicAdd(&cnt[pairs[i].y - bstart], 1);
    __syncthreads();

    // wave 0: exclusive scan of cnt[0..bn) -> cur[ln] = e0 + prefix
    if (t < 64) {
        int running = 0;
        for (int base2 = 0; base2 < bn; base2 += 64) {
            int idx2 = base2 + t;
            int v = (idx2 < bn) ? cnt[idx2] : 0;
            int orig = v;
            #pragma unroll
            for (int off = 1; off < 64; off <<= 1) {
                int tmp = __shfl_up(v, off);
                if (t >= off) v += tmp;
            }
            if (idx2 < bn) cur[idx2] = e0 + running + (v - orig);
            running += __shfl(v, 63);
        }
    }
    __syncthreads();

    for (int ln = t; ln < bn; ln += 256) {
        rowptr[bstart + ln] = cur[ln];
        dinv[bstart + ln] = rsqrtf((float)cnt[ln] + 1.0f);
    }
    if (b == 0 && t == 0) rowptr[n] = ne;
    __syncthreads();

    for (int i = e0 + t; i < e1; i += 256) {
        int2 p = pairs[i];
        int slot = atomicAdd(&cur[p.y - bstart], 1);
        csr_src[slot] = p.x;
    }
}

// ---------------- compute kernels -----------------------------------------

// A[row][c] = bf16( ((optionally relu(X+bin)) @ W)[row][c] * dinv[row] )
__global__ __launch_bounds__(256) void lin64_bf16(const float* __restrict__ X,
                                                  const float* __restrict__ bin,
                                                  const float* __restrict__ W,
                                                  const float* __restrict__ dinv,
                                                  __hip_bfloat16* __restrict__ Y,
                                                  int nrows) {
    __shared__ float sW[64 * 64];
    __shared__ float sX[4][64];
    int t = threadIdx.x;
    for (int i = t; i < 64 * 64; i += 256) sW[i] = W[i];
    int lane = t & 63;
    int w = t >> 6;
    int row = blockIdx.x * 4 + w;
    if (row < nrows) {
        float v = X[(size_t)row * 64 + lane];
        if (bin) v = fmaxf(v + bin[lane], 0.0f);
        sX[w][lane] = v;
    }
    __syncthreads();
    if (row < nrows) {
        float acc = 0.0f;
        #pragma unroll
        for (int k = 0; k < 64; ++k)
            acc = fmaf(sX[w][k], sW[k * 64 + lane], acc);
        Y[(size_t)row * 64 + lane] = __float2bfloat16(acc * dinv[row]);
    }
}

// B[d][c] = dinv[d] * ( A[d][c] + sum_{s in CSR row d} A[s][c] )
__global__ __launch_bounds__(256) void gcn_gather(const __hip_bfloat16* __restrict__ A,
                                                  const float* __restrict__ dinv,
                                                  const int* __restrict__ rowptr,
                                                  const int* __restrict__ csr_src,
                                                  float* __restrict__ B, int n) {
    int t = threadIdx.x;
    int node = blockIdx.x * 4 + (t >> 6);
    int c = t & 63;
    if (node >= n) return;
    float acc = __bfloat162float(A[(size_t)node * 64 + c]);   // self loop
    int beg = rowptr[node], end = rowptr[node + 1];
    for (int chunk = beg; chunk < end; chunk += 64) {
        int m = end - chunk;
        if (m > 64) m = 64;
        int sl = (c < m) ? csr_src[chunk + c] : 0;            // coalesced
        int j = 0;
        for (; j + 4 <= m; j += 4) {
            int s0 = __shfl(sl, j);
            int s1 = __shfl(sl, j + 1);
            int s2 = __shfl(sl, j + 2);
            int s3 = __shfl(sl, j + 3);
            float v0 = __bfloat162float(A[(size_t)s0 * 64 + c]);
            float v1 = __bfloat162float(A[(size_t)s1 * 64 + c]);
            float v2 = __bfloat162float(A[(size_t)s2 * 64 + c]);
            float v3 = __bfloat162float(A[(size_t)s3 * 64 + c]);
            acc += (v0 + v1) + (v2 + v3);
        }
        for (; j < m; ++j) {
            int s = __shfl(sl, j);
            acc += __bfloat162float(A[(size_t)s * 64 + c]);
        }
    }
    B[(size_t)node * 64 + c] = acc * dinv[node];
}

// Segmented pooling over sorted batch (relu(X+b) applied on the fly)
#define POOL_WIN 512
__global__ __launch_bounds__(256) void pool_seg(const float* __restrict__ X,
                                                const float* __restrict__ b,
                                                const void* __restrict__ batch,
                                                const int* __restrict__ flag,
                                                float* __restrict__ sums,
                                                float* __restrict__ counts, int n) {
    int t = threadIdx.x;
    int c = t & 63;
    int w = t >> 6;
    int base = blockIdx.x * POOL_WIN;
    int is64 = flag[0];
    float bc = b[c];
    float acc = 0.0f, cnt = 0.0f;
    int cur = -1;
    int lim = base + POOL_WIN;
    if (lim > n) lim = n;
    for (int i = base + w; i < lim; i += 4) {
        int g = idx_at(batch, i, is64);
        if (g != cur) {
            if (cur >= 0) {
                atomicAdd(&sums[(size_t)cur * 64 + c], acc);
                if (c == 0) atomicAdd(&counts[cur], cnt);
            }
            cur = g; acc = 0.0f; cnt = 0.0f;
        }
        acc += fmaxf(X[(size_t)i * 64 + c] + bc, 0.0f);
        cnt += 1.0f;
    }
    if (cur >= 0) {
        atomicAdd(&sums[(size_t)cur * 64 + c], acc);
        if (c == 0) atomicAdd(&counts[cur], cnt);
    }
}

// One block (64 threads) per graph: pooled -> mu/logvar -> z -> recon
__global__ __launch_bounds__(64) void vae_head(const float* __restrict__ sums,
                                               const float* __restrict__ counts,
                                               const float* __restrict__ Wmu,
                                               const float* __restrict__ bmu,
                                               const float* __restrict__ Wlv,
                                               const float* __restrict__ blv,
                                               const float* __restrict__ Wd1,
                                               const float* __restrict__ bd1,
                                               const float* __restrict__ Wd2,
                                               const float* __restrict__ bd2,
                                               float* __restrict__ out) {
    int g = blockIdx.x;
    int t = threadIdx.x;  // 64 threads
    __shared__ float sp[64];
    __shared__ float sz[32];
    __shared__ float sh[64];

    float cnt = fmaxf(counts[g], 1.0f);
    sp[t] = sums[(size_t)g * 64 + t] / cnt;
    __syncthreads();

    if (t < 32) {
        float mu = bmu[t];
        float lv = blv[t];
        #pragma unroll
        for (int k = 0; k < 64; ++k) {
            float pk = sp[k];
            mu = fmaf(pk, Wmu[k * 32 + t], mu);
            lv = fmaf(pk, Wlv[k * 32 + t], lv);
        }
        unsigned idx = (unsigned)(g * 32 + t);
        float eps = jax_normal_4232(idx);
        float z = fmaf(eps, expf(0.5f * lv), mu);
        sz[t] = z;
        out[16384 + (size_t)g * 32 + t] = mu;       // mu block
        out[24576 + (size_t)g * 32 + t] = lv;       // logvar block
    }
    __syncthreads();

    float h = bd1[t];
    #pragma unroll
    for (int k = 0; k < 32; ++k) h = fmaf(sz[k], Wd1[k * 64 + t], h);
    h = fmaxf(h, 0.0f);
    sh[t] = h;
    __syncthreads();

    float r = bd2[t];
    #pragma unroll
    for (int k = 0; k < 64; ++k) r = fmaf(sh[k], Wd2[k * 64 + t], r);
    out[(size_t)g * 64 + t] = r;                    // recon block
}

// ---------------- launch ----------------------------------------------------

extern "C" void kernel_launch(void* const* d_in, const int* in_sizes, int n_in,
                              void* d_out, int out_size, void* d_ws, size_t ws_size,
                              hipStream_t stream) {
    const float* x    = (const float*)d_in[0];
    const void*  ei   = d_in[1];
    const void*  batch= d_in[2];
    const float* W1   = (const float*)d_in[3];
    const float* b1   = (const float*)d_in[4];
    const float* W2   = (const float*)d_in[5];
    const float* b2   = (const float*)d_in[6];
    const float* Wmu  = (const float*)d_in[7];
    const float* bmu  = (const float*)d_in[8];
    const float* Wlv  = (const float*)d_in[9];
    const float* blv  = (const float*)d_in[10];
    const float* Wd1  = (const float*)d_in[11];
    const float* bd1  = (const float*)d_in[12];
    const float* Wd2  = (const float*)d_in[13];
    const float* bd2  = (const float*)d_in[14];

    const int N = in_sizes[0] / 64;       // 100000
    const int E = in_sizes[1] / 2;        // 1000000
    const int G = 256;

    const int NPB = (N + NBK - 1) / NBK;          // 391 nodes per bucket
    const int nbu = (N + NPB - 1) / NPB;          // 256 buckets

    float* out = (float*)d_out;

    // workspace layout
    float* dinv = (float*)d_ws;                          // Npad floats
    __hip_bfloat16* A = (__hip_bfloat16*)(dinv + ((N + 255) & ~255)); // N*64 bf16
    float* B    = (float*)(A + (size_t)N * 64);          // N*64 fp32
    float* sums = B + (size_t)N * 64;                    // G*64
    float* cnts = sums + (size_t)G * 64;                 // G
    int*   flag = (int*)(cnts + G);                      // 1 (+pad to 256)
    int*   rowptr = flag + 256;                          // N+1 (+pad)
    int*   bcnt = rowptr + ((N + 256) & ~255);           // 256
    int*   ebase = bcnt + 256;                           // 257 (+pad)
    int*   gcur = ebase + 512;                           // 256
    int*   csr_src = gcur + 256;                         // E
    int2*  pairs = (int2*)(csr_src + ((E + 1) & ~1));    // E (8B aligned)

    const int blkRows  = (N + 3) / 4;
    const int blkPool  = (N + POOL_WIN - 1) / POOL_WIN;
    const int chunkE   = (E + NBK - 1) / NBK;            // edges per fill block

    // index dtype detection
    detect_idx64<<<1, 256, 0, stream>>>((const unsigned*)ei, E, flag);

    // bucketed CSR build
    hipMemsetAsync(bcnt, 0, NBK * sizeof(int), stream);
    bucket_count<<<NBK, 256, 0, stream>>>(ei, flag, bcnt, E, NPB, chunkE);
    bucket_scan<<<1, NBK, 0, stream>>>(bcnt, ebase, gcur, nbu, E);
    bucket_fill<<<NBK, 256, 0, stream>>>(ei, flag, gcur, pairs, E, NPB, chunkE);
    csr_build<<<nbu, 256, 0, stream>>>(pairs, ebase, rowptr, dinv, csr_src,
                                       N, E, NPB);

    // conv1: A = bf16(x@W1 * dinv) ; B = gather(A) * dinv
    lin64_bf16<<<blkRows, 256, 0, stream>>>(x, nullptr, W1, dinv, A, N);
    gcn_gather<<<blkRows, 256, 0, stream>>>(A, dinv, rowptr, csr_src, B, N);

    // conv2: A = bf16(relu(B+b1)@W2 * dinv) ; B = gather(A) * dinv
    lin64_bf16<<<blkRows, 256, 0, stream>>>(B, b1, W2, dinv, A, N);
    gcn_gather<<<blkRows, 256, 0, stream>>>(A, dinv, rowptr, csr_src, B, N);

    // pool (applies relu(B+b2)) + head
    hipMemsetAsync(sums, 0, (size_t)(G * 64 + G) * sizeof(float), stream);
    pool_seg<<<blkPool, 256, 0, stream>>>(B, b2, batch, flag, sums, cnts, N);
    vae_head<<<G, 64, 0, stream>>>(sums, cnts, Wmu, bmu, Wlv, blv,
                                   Wd1, bd1, Wd2, bd2, out);
}

// Round 8
// 257.002 us; speedup vs baseline: 4.2879x; 1.1887x over previous
//
#include <hip/hip_runtime.h>
#include <hip/hip_bf16.h>

// ---------------- JAX threefry2x32 (partitionable) + normal(key=42) --------

__device__ inline unsigned rotl32(unsigned x, unsigned r) {
    return (x << r) | (x >> (32 - r));
}

__device__ inline void threefry2x32_042(unsigned c0, unsigned c1,
                                        unsigned& o0, unsigned& o1) {
    const unsigned k0 = 0u, k1 = 42u;
    unsigned ks[3] = { k0, k1, k0 ^ k1 ^ 0x1BD11BDAu };
    unsigned x0 = c0 + ks[0];
    unsigned x1 = c1 + ks[1];
    const unsigned rotA[4] = {13u, 15u, 26u, 6u};
    const unsigned rotB[4] = {17u, 29u, 16u, 24u};

    #pragma unroll
    for (int i = 0; i < 5; ++i) {
        #pragma unroll
        for (int j = 0; j < 4; ++j) {
            unsigned r = (i & 1) ? rotB[j] : rotA[j];
            x0 += x1;
            x1 = rotl32(x1, r);
            x1 ^= x0;
        }
        x0 += ks[(i + 1) % 3];
        x1 += ks[(i + 2) % 3] + (unsigned)(i + 1);
    }
    o0 = x0; o1 = x1;
}

__device__ inline float erfinv_f32(float x) {
    float w = -log1pf(-x * x);
    float p;
    if (w < 5.0f) {
        w -= 2.5f;
        p = 2.81022636e-08f;
        p = fmaf(p, w, 3.43273939e-07f);
        p = fmaf(p, w, -3.5233877e-06f);
        p = fmaf(p, w, -4.39150654e-06f);
        p = fmaf(p, w, 0.00021858087f);
        p = fmaf(p, w, -0.00125372503f);
        p = fmaf(p, w, -0.00417768164f);
        p = fmaf(p, w, 0.246640727f);
        p = fmaf(p, w, 1.50140941f);
    } else {
        w = sqrtf(w) - 3.0f;
        p = -0.000200214257f;
        p = fmaf(p, w, 0.000100950558f);
        p = fmaf(p, w, 0.00134934322f);
        p = fmaf(p, w, -0.00367342844f);
        p = fmaf(p, w, 0.00573950773f);
        p = fmaf(p, w, -0.0076224613f);
        p = fmaf(p, w, 0.00943887047f);
        p = fmaf(p, w, 1.00167406f);
        p = fmaf(p, w, 2.83297682f);
    }
    return p * x;
}

__device__ inline float jax_normal_4232(unsigned idx) {
    unsigned o0, o1;
    threefry2x32_042(0u, idx, o0, o1);
    unsigned bits = o0 ^ o1;
    unsigned fb = (bits >> 9) | 0x3f800000u;
    float f = __uint_as_float(fb) - 1.0f;              // [0, 1)
    const float lo = -0.99999994f;                     // nextafter(-1, 0)
    float u = f * (1.0f - lo) + lo;
    u = fmaxf(u, lo);
    return 1.41421356f * erfinv_f32(u);
}

// ---------------- int64/int32 index handling -------------------------------

__device__ inline int idx_at(const void* p, long long i, int is64) {
    return is64 ? (int)((const long long*)p)[i] : ((const int*)p)[i];
}

__global__ __launch_bounds__(256) void detect_idx64(const unsigned* __restrict__ raw,
                                                    int ne, int* flag) {
    __shared__ int nz;
    if (threadIdx.x == 0) nz = 0;
    __syncthreads();
    int stride = ne / 2048;
    if (stride < 1) stride = 1;
    for (int k = threadIdx.x; k < 2048; k += 256) {
        long long j = (long long)k * stride;
        if (j < ne && raw[2 * j + 1] != 0u) nz = 1;
    }
    __syncthreads();
    if (threadIdx.x == 0) flag[0] = (nz == 0) ? 1 : 0;
}

// ---------------- bucketed CSR construction --------------------------------

#define NBK 256

__global__ __launch_bounds__(256) void bucket_count(const void* __restrict__ ei,
                                                    const int* __restrict__ flag,
                                                    int* __restrict__ bcnt,
                                                    int ne, int npb, int chunk) {
    __shared__ int hist[NBK];
    int t = threadIdx.x;
    hist[t] = 0;
    __syncthreads();
    int is64 = flag[0];
    int c0 = blockIdx.x * chunk;
    int c1 = c0 + chunk; if (c1 > ne) c1 = ne;
    for (int i = c0 + t; i < c1; i += 256) {
        int d = idx_at(ei, (long long)ne + i, is64);
        atomicAdd(&hist[d / npb], 1);
    }
    __syncthreads();
    if (hist[t] > 0) atomicAdd(&bcnt[t], hist[t]);
}

__global__ __launch_bounds__(256) void bucket_scan(const int* __restrict__ bcnt,
                                                   int* __restrict__ ebase,
                                                   int* __restrict__ gcur,
                                                   int nbu, int ne) {
    __shared__ int s[NBK];
    int t = threadIdx.x;
    int v = (t < nbu) ? bcnt[t] : 0;
    s[t] = v;
    __syncthreads();
    for (int off = 1; off < NBK; off <<= 1) {
        int tmp = (t >= off) ? s[t - off] : 0;
        __syncthreads();
        s[t] += tmp;
        __syncthreads();
    }
    int excl = s[t] - v;
    if (t < nbu) { ebase[t] = excl; gcur[t] = excl; }
    if (t == 0) ebase[nbu] = ne;
}

__global__ __launch_bounds__(256) void bucket_fill(const void* __restrict__ ei,
                                                   const int* __restrict__ flag,
                                                   int* __restrict__ gcur,
                                                   int2* __restrict__ pairs,
                                                   int ne, int npb, int chunk) {
    __shared__ int hist[NBK];
    __shared__ int basecur[NBK];
    int t = threadIdx.x;
    hist[t] = 0;
    __syncthreads();
    int is64 = flag[0];
    int c0 = blockIdx.x * chunk;
    int c1 = c0 + chunk; if (c1 > ne) c1 = ne;
    for (int i = c0 + t; i < c1; i += 256) {
        int d = idx_at(ei, (long long)ne + i, is64);
        atomicAdd(&hist[d / npb], 1);
    }
    __syncthreads();
    if (hist[t] > 0) basecur[t] = atomicAdd(&gcur[t], hist[t]);
    __syncthreads();
    for (int i = c0 + t; i < c1; i += 256) {
        int s = idx_at(ei, i, is64);
        int d = idx_at(ei, (long long)ne + i, is64);
        int slot = atomicAdd(&basecur[d / npb], 1);
        pairs[slot] = make_int2(s, d);
    }
}

#define NPB_MAX 512
__global__ __launch_bounds__(256) void csr_build(const int2* __restrict__ pairs,
                                                 const int* __restrict__ ebase,
                                                 int* __restrict__ rowptr,
                                                 float* __restrict__ dinv,
                                                 int* __restrict__ csr_src,
                                                 int n, int ne, int npb) {
    __shared__ int cnt[NPB_MAX];
    __shared__ int cur[NPB_MAX];
    int b = blockIdx.x;
    int t = threadIdx.x;
    int bstart = b * npb;
    int bn = n - bstart; if (bn > npb) bn = npb;
    int e0 = ebase[b], e1 = ebase[b + 1];

    for (int i = t; i < bn; i += 256) cnt[i] = 0;
    __syncthreads();
    for (int i = e0 + t; i < e1; i += 256)
        atomicAdd(&cnt[pairs[i].y - bstart], 1);
    __syncthreads();

    if (t < 64) {
        int running = 0;
        for (int base2 = 0; base2 < bn; base2 += 64) {
            int idx2 = base2 + t;
            int v = (idx2 < bn) ? cnt[idx2] : 0;
            int orig = v;
            #pragma unroll
            for (int off = 1; off < 64; off <<= 1) {
                int tmp = __shfl_up(v, off);
                if (t >= off) v += tmp;
            }
            if (idx2 < bn) cur[idx2] = e0 + running + (v - orig);
            running += __shfl(v, 63);
        }
    }
    __syncthreads();

    for (int ln = t; ln < bn; ln += 256) {
        rowptr[bstart + ln] = cur[ln];
        dinv[bstart + ln] = rsqrtf((float)cnt[ln] + 1.0f);
    }
    if (b == 0 && t == 0) rowptr[n] = ne;
    __syncthreads();

    for (int i = e0 + t; i < e1; i += 256) {
        int2 p = pairs[i];
        int slot = atomicAdd(&cur[p.y - bstart], 1);
        csr_src[slot] = p.x;
    }
}

// ---------------- compute kernels -----------------------------------------

__device__ inline float ld_val(const float* p, size_t i) { return p[i]; }
__device__ inline float ld_val(const __hip_bfloat16* p, size_t i) {
    return __bfloat162float(p[i]);
}

// Y[row][c] = bf16( ((optionally relu(X+bin)) @ W)[row][c] * dinv[row] )
template <typename TIN>
__global__ __launch_bounds__(256) void lin64_bf16(const TIN* __restrict__ X,
                                                  const float* __restrict__ bin,
                                                  const float* __restrict__ W,
                                                  const float* __restrict__ dinv,
                                                  __hip_bfloat16* __restrict__ Y,
                                                  int nrows) {
    __shared__ float sW[64 * 64];
    __shared__ float sX[4][64];
    int t = threadIdx.x;
    for (int i = t; i < 64 * 64; i += 256) sW[i] = W[i];
    int lane = t & 63;
    int w = t >> 6;
    int row = blockIdx.x * 4 + w;
    if (row < nrows) {
        float v = ld_val(X, (size_t)row * 64 + lane);
        if (bin) v = fmaxf(v + bin[lane], 0.0f);
        sX[w][lane] = v;
    }
    __syncthreads();
    if (row < nrows) {
        float acc = 0.0f;
        #pragma unroll
        for (int k = 0; k < 64; ++k)
            acc = fmaf(sX[w][k], sW[k * 64 + lane], acc);
        Y[(size_t)row * 64 + lane] = __float2bfloat16(acc * dinv[row]);
    }
}

// B[d][c] = bf16( dinv[d] * ( A[d][c] + sum_{s in CSR row d} A[s][c] ) )
__global__ __launch_bounds__(256) void gcn_gather(const __hip_bfloat16* __restrict__ A,
                                                  const float* __restrict__ dinv,
                                                  const int* __restrict__ rowptr,
                                                  const int* __restrict__ csr_src,
                                                  __hip_bfloat16* __restrict__ B, int n) {
    int t = threadIdx.x;
    int node = blockIdx.x * 4 + (t >> 6);
    int c = t & 63;
    if (node >= n) return;
    float acc = __bfloat162float(A[(size_t)node * 64 + c]);   // self loop
    int beg = rowptr[node], end = rowptr[node + 1];
    for (int chunk = beg; chunk < end; chunk += 64) {
        int m = end - chunk;
        if (m > 64) m = 64;
        int sl = (c < m) ? csr_src[chunk + c] : 0;            // coalesced
        int j = 0;
        for (; j + 4 <= m; j += 4) {
            int s0 = __shfl(sl, j);
            int s1 = __shfl(sl, j + 1);
            int s2 = __shfl(sl, j + 2);
            int s3 = __shfl(sl, j + 3);
            float v0 = __bfloat162float(A[(size_t)s0 * 64 + c]);
            float v1 = __bfloat162float(A[(size_t)s1 * 64 + c]);
            float v2 = __bfloat162float(A[(size_t)s2 * 64 + c]);
            float v3 = __bfloat162float(A[(size_t)s3 * 64 + c]);
            acc += (v0 + v1) + (v2 + v3);
        }
        for (; j < m; ++j) {
            int s = __shfl(sl, j);
            acc += __bfloat162float(A[(size_t)s * 64 + c]);
        }
    }
    B[(size_t)node * 64 + c] = __float2bfloat16(acc * dinv[node]);
}

// Segmented pooling over sorted batch: one wave per 32 contiguous nodes,
// 2-node unrolled (2 independent row loads in flight), register accumulate,
// flush on graph transition.
#define POOL_NPW 32
__global__ __launch_bounds__(256) void pool_seg(const __hip_bfloat16* __restrict__ X,
                                                const float* __restrict__ b,
                                                const void* __restrict__ batch,
                                                const int* __restrict__ flag,
                                                float* __restrict__ sums,
                                                float* __restrict__ counts, int n) {
    int t = threadIdx.x;
    int c = t & 63;
    int wid = blockIdx.x * 4 + (t >> 6);
    int s0 = wid * POOL_NPW;
    if (s0 >= n) return;
    int s1 = s0 + POOL_NPW; if (s1 > n) s1 = n;
    int is64 = flag[0];
    float bc = b[c];
    float acc = 0.0f, cnt = 0.0f;
    int cur = idx_at(batch, s0, is64);
    int i = s0;
    for (; i + 2 <= s1; i += 2) {
        int g0 = idx_at(batch, i, is64);
        int g1 = idx_at(batch, i + 1, is64);
        float v0 = __bfloat162float(X[(size_t)i * 64 + c]);
        float v1 = __bfloat162float(X[(size_t)(i + 1) * 64 + c]);
        if (g0 != cur) {
            atomicAdd(&sums[(size_t)cur * 64 + c], acc);
            if (c == 0) atomicAdd(&counts[cur], cnt);
            acc = 0.0f; cnt = 0.0f; cur = g0;
        }
        acc += fmaxf(v0 + bc, 0.0f); cnt += 1.0f;
        if (g1 != cur) {
            atomicAdd(&sums[(size_t)cur * 64 + c], acc);
            if (c == 0) atomicAdd(&counts[cur], cnt);
            acc = 0.0f; cnt = 0.0f; cur = g1;
        }
        acc += fmaxf(v1 + bc, 0.0f); cnt += 1.0f;
    }
    if (i < s1) {
        int g0 = idx_at(batch, i, is64);
        float v0 = __bfloat162float(X[(size_t)i * 64 + c]);
        if (g0 != cur) {
            atomicAdd(&sums[(size_t)cur * 64 + c], acc);
            if (c == 0) atomicAdd(&counts[cur], cnt);
            acc = 0.0f; cnt = 0.0f; cur = g0;
        }
        acc += fmaxf(v0 + bc, 0.0f); cnt += 1.0f;
    }
    atomicAdd(&sums[(size_t)cur * 64 + c], acc);
    if (c == 0) atomicAdd(&counts[cur], cnt);
}

// One block (64 threads) per graph: pooled -> mu/logvar -> z -> recon
__global__ __launch_bounds__(64) void vae_head(const float* __restrict__ sums,
                                               const float* __restrict__ counts,
                                               const float* __restrict__ Wmu,
                                               const float* __restrict__ bmu,
                                               const float* __restrict__ Wlv,
                                               const float* __restrict__ blv,
                                               const float* __restrict__ Wd1,
                                               const float* __restrict__ bd1,
                                               const float* __restrict__ Wd2,
                                               const float* __restrict__ bd2,
                                               float* __restrict__ out) {
    int g = blockIdx.x;
    int t = threadIdx.x;  // 64 threads
    __shared__ float sp[64];
    __shared__ float sz[32];
    __shared__ float sh[64];

    float cnt = fmaxf(counts[g], 1.0f);
    sp[t] = sums[(size_t)g * 64 + t] / cnt;
    __syncthreads();

    if (t < 32) {
        float mu = bmu[t];
        float lv = blv[t];
        #pragma unroll
        for (int k = 0; k < 64; ++k) {
            float pk = sp[k];
            mu = fmaf(pk, Wmu[k * 32 + t], mu);
            lv = fmaf(pk, Wlv[k * 32 + t], lv);
        }
        unsigned idx = (unsigned)(g * 32 + t);
        float eps = jax_normal_4232(idx);
        float z = fmaf(eps, expf(0.5f * lv), mu);
        sz[t] = z;
        out[16384 + (size_t)g * 32 + t] = mu;       // mu block
        out[24576 + (size_t)g * 32 + t] = lv;       // logvar block
    }
    __syncthreads();

    float h = bd1[t];
    #pragma unroll
    for (int k = 0; k < 32; ++k) h = fmaf(sz[k], Wd1[k * 64 + t], h);
    h = fmaxf(h, 0.0f);
    sh[t] = h;
    __syncthreads();

    float r = bd2[t];
    #pragma unroll
    for (int k = 0; k < 64; ++k) r = fmaf(sh[k], Wd2[k * 64 + t], r);
    out[(size_t)g * 64 + t] = r;                    // recon block
}

// ---------------- launch ----------------------------------------------------

extern "C" void kernel_launch(void* const* d_in, const int* in_sizes, int n_in,
                              void* d_out, int out_size, void* d_ws, size_t ws_size,
                              hipStream_t stream) {
    const float* x    = (const float*)d_in[0];
    const void*  ei   = d_in[1];
    const void*  batch= d_in[2];
    const float* W1   = (const float*)d_in[3];
    const float* b1   = (const float*)d_in[4];
    const float* W2   = (const float*)d_in[5];
    const float* b2   = (const float*)d_in[6];
    const float* Wmu  = (const float*)d_in[7];
    const float* bmu  = (const float*)d_in[8];
    const float* Wlv  = (const float*)d_in[9];
    const float* blv  = (const float*)d_in[10];
    const float* Wd1  = (const float*)d_in[11];
    const float* bd1  = (const float*)d_in[12];
    const float* Wd2  = (const float*)d_in[13];
    const float* bd2  = (const float*)d_in[14];

    const int N = in_sizes[0] / 64;       // 100000
    const int E = in_sizes[1] / 2;        // 1000000
    const int G = 256;

    const int NPB = (N + NBK - 1) / NBK;          // 391 nodes per bucket
    const int nbu = (N + NPB - 1) / NPB;          // 256 buckets

    float* out = (float*)d_out;

    // workspace layout
    float* dinv = (float*)d_ws;                          // Npad floats
    __hip_bfloat16* A = (__hip_bfloat16*)(dinv + ((N + 255) & ~255)); // N*64 bf16
    __hip_bfloat16* B = A + (size_t)N * 64;              // N*64 bf16
    float* sums = (float*)(B + (size_t)N * 64);          // G*64
    float* cnts = sums + (size_t)G * 64;                 // G
    int*   flag = (int*)(cnts + G);                      // 1 (+pad to 256)
    int*   rowptr = flag + 256;                          // N+1 (+pad)
    int*   bcnt = rowptr + ((N + 256) & ~255);           // 256
    int*   ebase = bcnt + 256;                           // 257 (+pad)
    int*   gcur = ebase + 512;                           // 256
    int*   csr_src = gcur + 256;                         // E
    int2*  pairs = (int2*)(csr_src + ((E + 1) & ~1));    // E (8B aligned)

    const int blkRows  = (N + 3) / 4;
    const int blkPool  = (N + POOL_NPW * 4 - 1) / (POOL_NPW * 4);
    const int chunkE   = (E + NBK - 1) / NBK;            // edges per fill block

    // index dtype detection
    detect_idx64<<<1, 256, 0, stream>>>((const unsigned*)ei, E, flag);

    // bucketed CSR build
    hipMemsetAsync(bcnt, 0, NBK * sizeof(int), stream);
    bucket_count<<<NBK, 256, 0, stream>>>(ei, flag, bcnt, E, NPB, chunkE);
    bucket_scan<<<1, NBK, 0, stream>>>(bcnt, ebase, gcur, nbu, E);
    bucket_fill<<<NBK, 256, 0, stream>>>(ei, flag, gcur, pairs, E, NPB, chunkE);
    csr_build<<<nbu, 256, 0, stream>>>(pairs, ebase, rowptr, dinv, csr_src,
                                       N, E, NPB);

    // conv1: A = bf16(x@W1 * dinv) ; B = bf16(gather(A) * dinv)
    lin64_bf16<float><<<blkRows, 256, 0, stream>>>(x, nullptr, W1, dinv, A, N);
    gcn_gather<<<blkRows, 256, 0, stream>>>(A, dinv, rowptr, csr_src, B, N);

    // conv2: A = bf16(relu(B+b1)@W2 * dinv) ; B = bf16(gather(A) * dinv)
    lin64_bf16<__hip_bfloat16><<<blkRows, 256, 0, stream>>>(B, b1, W2, dinv, A, N);
    gcn_gather<<<blkRows, 256, 0, stream>>>(A, dinv, rowptr, csr_src, B, N);

    // pool (applies relu(B+b2)) + head
    hipMemsetAsync(sums, 0, (size_t)(G * 64 + G) * sizeof(float), stream);
    pool_seg<<<blkPool, 256, 0, stream>>>(B, b2, batch, flag, sums, cnts, N);
    vae_head<<<G, 64, 0, stream>>>(sums, cnts, Wmu, bmu, Wlv, blv,
                                   Wd1, bd1, Wd2, bd2, out);
}

// Round 9
// 184.340 us; speedup vs baseline: 5.9781x; 1.3942x over previous
//
#include <hip/hip_runtime.h>
#include <hip/hip_bf16.h>

typedef __attribute__((ext_vector_type(8))) short bf16x8;
typedef __attribute__((ext_vector_type(4))) float f32x4;

__device__ inline unsigned short f2bf(float f) {          // RNE, matches __float2bfloat16
    unsigned u = __float_as_uint(f);
    unsigned r = u + 0x7fffu + ((u >> 16) & 1u);
    return (unsigned short)(r >> 16);
}
__device__ inline float bf2f(unsigned short s) {
    return __uint_as_float((unsigned)s << 16);
}

// ---------------- JAX threefry2x32 (partitionable) + normal(key=42) --------

__device__ inline unsigned rotl32(unsigned x, unsigned r) {
    return (x << r) | (x >> (32 - r));
}

__device__ inline void threefry2x32_042(unsigned c0, unsigned c1,
                                        unsigned& o0, unsigned& o1) {
    const unsigned k0 = 0u, k1 = 42u;
    unsigned ks[3] = { k0, k1, k0 ^ k1 ^ 0x1BD11BDAu };
    unsigned x0 = c0 + ks[0];
    unsigned x1 = c1 + ks[1];
    const unsigned rotA[4] = {13u, 15u, 26u, 6u};
    const unsigned rotB[4] = {17u, 29u, 16u, 24u};

    #pragma unroll
    for (int i = 0; i < 5; ++i) {
        #pragma unroll
        for (int j = 0; j < 4; ++j) {
            unsigned r = (i & 1) ? rotB[j] : rotA[j];
            x0 += x1;
            x1 = rotl32(x1, r);
            x1 ^= x0;
        }
        x0 += ks[(i + 1) % 3];
        x1 += ks[(i + 2) % 3] + (unsigned)(i + 1);
    }
    o0 = x0; o1 = x1;
}

__device__ inline float erfinv_f32(float x) {
    float w = -log1pf(-x * x);
    float p;
    if (w < 5.0f) {
        w -= 2.5f;
        p = 2.81022636e-08f;
        p = fmaf(p, w, 3.43273939e-07f);
        p = fmaf(p, w, -3.5233877e-06f);
        p = fmaf(p, w, -4.39150654e-06f);
        p = fmaf(p, w, 0.00021858087f);
        p = fmaf(p, w, -0.00125372503f);
        p = fmaf(p, w, -0.00417768164f);
        p = fmaf(p, w, 0.246640727f);
        p = fmaf(p, w, 1.50140941f);
    } else {
        w = sqrtf(w) - 3.0f;
        p = -0.000200214257f;
        p = fmaf(p, w, 0.000100950558f);
        p = fmaf(p, w, 0.00134934322f);
        p = fmaf(p, w, -0.00367342844f);
        p = fmaf(p, w, 0.00573950773f);
        p = fmaf(p, w, -0.0076224613f);
        p = fmaf(p, w, 0.00943887047f);
        p = fmaf(p, w, 1.00167406f);
        p = fmaf(p, w, 2.83297682f);
    }
    return p * x;
}

__device__ inline float jax_normal_4232(unsigned idx) {
    unsigned o0, o1;
    threefry2x32_042(0u, idx, o0, o1);
    unsigned bits = o0 ^ o1;
    unsigned fb = (bits >> 9) | 0x3f800000u;
    float f = __uint_as_float(fb) - 1.0f;              // [0, 1)
    const float lo = -0.99999994f;                     // nextafter(-1, 0)
    float u = f * (1.0f - lo) + lo;
    u = fmaxf(u, lo);
    return 1.41421356f * erfinv_f32(u);
}

// ---------------- int64/int32 index handling -------------------------------

__device__ inline int idx_at(const void* p, long long i, int is64) {
    return is64 ? (int)((const long long*)p)[i] : ((const int*)p)[i];
}

__global__ __launch_bounds__(256) void detect_idx64(const unsigned* __restrict__ raw,
                                                    int ne, int* flag) {
    __shared__ int nz;
    if (threadIdx.x == 0) nz = 0;
    __syncthreads();
    int stride = ne / 2048;
    if (stride < 1) stride = 1;
    for (int k = threadIdx.x; k < 2048; k += 256) {
        long long j = (long long)k * stride;
        if (j < ne && raw[2 * j + 1] != 0u) nz = 1;
    }
    __syncthreads();
    if (threadIdx.x == 0) flag[0] = (nz == 0) ? 1 : 0;
}

// ---------------- bucketed CSR construction --------------------------------

#define NBK 256

__global__ __launch_bounds__(256) void bucket_count(const void* __restrict__ ei,
                                                    const int* __restrict__ flag,
                                                    int* __restrict__ bcnt,
                                                    int ne, int npb, int chunk) {
    __shared__ int hist[NBK];
    int t = threadIdx.x;
    hist[t] = 0;
    __syncthreads();
    int is64 = flag[0];
    int c0 = blockIdx.x * chunk;
    int c1 = c0 + chunk; if (c1 > ne) c1 = ne;
    for (int i = c0 + t; i < c1; i += 256) {
        int d = idx_at(ei, (long long)ne + i, is64);
        atomicAdd(&hist[d / npb], 1);
    }
    __syncthreads();
    if (hist[t] > 0) atomicAdd(&bcnt[t], hist[t]);
}

__global__ __launch_bounds__(256) void bucket_scan(const int* __restrict__ bcnt,
                                                   int* __restrict__ ebase,
                                                   int* __restrict__ gcur,
                                                   int nbu, int ne) {
    __shared__ int s[NBK];
    int t = threadIdx.x;
    int v = (t < nbu) ? bcnt[t] : 0;
    s[t] = v;
    __syncthreads();
    for (int off = 1; off < NBK; off <<= 1) {
        int tmp = (t >= off) ? s[t - off] : 0;
        __syncthreads();
        s[t] += tmp;
        __syncthreads();
    }
    int excl = s[t] - v;
    if (t < nbu) { ebase[t] = excl; gcur[t] = excl; }
    if (t == 0) ebase[nbu] = ne;
}

__global__ __launch_bounds__(256) void bucket_fill(const void* __restrict__ ei,
                                                   const int* __restrict__ flag,
                                                   int* __restrict__ gcur,
                                                   int2* __restrict__ pairs,
                                                   int ne, int npb, int chunk) {
    __shared__ int hist[NBK];
    __shared__ int basecur[NBK];
    int t = threadIdx.x;
    hist[t] = 0;
    __syncthreads();
    int is64 = flag[0];
    int c0 = blockIdx.x * chunk;
    int c1 = c0 + chunk; if (c1 > ne) c1 = ne;
    for (int i = c0 + t; i < c1; i += 256) {
        int d = idx_at(ei, (long long)ne + i, is64);
        atomicAdd(&hist[d / npb], 1);
    }
    __syncthreads();
    if (hist[t] > 0) basecur[t] = atomicAdd(&gcur[t], hist[t]);
    __syncthreads();
    for (int i = c0 + t; i < c1; i += 256) {
        int s = idx_at(ei, i, is64);
        int d = idx_at(ei, (long long)ne + i, is64);
        int slot = atomicAdd(&basecur[d / npb], 1);
        pairs[slot] = make_int2(s, d);
    }
}

#define NPB_MAX 512
__global__ __launch_bounds__(256) void csr_build(const int2* __restrict__ pairs,
                                                 const int* __restrict__ ebase,
                                                 int* __restrict__ rowptr,
                                                 float* __restrict__ dinv,
                                                 int* __restrict__ csr_src,
                                                 int n, int ne, int npb) {
    __shared__ int cnt[NPB_MAX];
    __shared__ int cur[NPB_MAX];
    int b = blockIdx.x;
    int t = threadIdx.x;
    int bstart = b * npb;
    int bn = n - bstart; if (bn > npb) bn = npb;
    int e0 = ebase[b], e1 = ebase[b + 1];

    for (int i = t; i < bn; i += 256) cnt[i] = 0;
    __syncthreads();
    for (int i = e0 + t; i < e1; i += 256)
        atomicAdd(&cnt[pairs[i].y - bstart], 1);
    __syncthreads();

    if (t < 64) {
        int running = 0;
        for (int base2 = 0; base2 < bn; base2 += 64) {
            int idx2 = base2 + t;
            int v = (idx2 < bn) ? cnt[idx2] : 0;
            int orig = v;
            #pragma unroll
            for (int off = 1; off < 64; off <<= 1) {
                int tmp = __shfl_up(v, off);
                if (t >= off) v += tmp;
            }
            if (idx2 < bn) cur[idx2] = e0 + running + (v - orig);
            running += __shfl(v, 63);
        }
    }
    __syncthreads();

    for (int ln = t; ln < bn; ln += 256) {
        rowptr[bstart + ln] = cur[ln];
        dinv[bstart + ln] = rsqrtf((float)cnt[ln] + 1.0f);
    }
    if (b == 0 && t == 0) rowptr[n] = ne;
    __syncthreads();

    for (int i = e0 + t; i < e1; i += 256) {
        int2 p = pairs[i];
        int slot = atomicAdd(&cur[p.y - bstart], 1);
        csr_src[slot] = p.x;
    }
}

// ---------------- MFMA 64x64 linear layers ---------------------------------
// One wave per 16-row tile: Y[16x64] = A[16x64] @ W[64x64], via
// mfma_f32_16x16x32_bf16 (2 K-steps x 4 col-blocks). W in registers.
// A-frag: row = lane&15, k = (lane>>4)*8 + j.  B-frag: col = lane&15, same k.
// C/D: col = lane&15, row = (lane>>4)*4 + reg.

__device__ inline void load_wfrags(const float* __restrict__ W,
                                   int cq, int cr, bf16x8 wf[2][4]) {
    #pragma unroll
    for (int ks = 0; ks < 2; ++ks)
        #pragma unroll
        for (int cb = 0; cb < 4; ++cb) {
            bf16x8 v;
            #pragma unroll
            for (int j = 0; j < 8; ++j) {
                int k = ks * 32 + cq * 8 + j;
                v[j] = (short)f2bf(W[k * 64 + cb * 16 + cr]);
            }
            wf[ks][cb] = v;
        }
}

__device__ inline void mfma_store(f32x4 acc[4], const float* __restrict__ dinv,
                                  unsigned short* __restrict__ Y,
                                  int rowbase, int cq, int cr, int nrows) {
    #pragma unroll
    for (int reg = 0; reg < 4; ++reg) {
        int r = rowbase + cq * 4 + reg;
        if (r < nrows) {
            float dv = dinv[r];
            #pragma unroll
            for (int cb = 0; cb < 4; ++cb)
                Y[(size_t)r * 64 + cb * 16 + cr] = f2bf(acc[cb][reg] * dv);
        }
    }
}

// conv1: X fp32, no bias/relu
__global__ __launch_bounds__(256) void lin64_mfma_f32(const float* __restrict__ X,
                                                      const float* __restrict__ W,
                                                      const float* __restrict__ dinv,
                                                      unsigned short* __restrict__ Y,
                                                      int nrows) {
    int t = threadIdx.x;
    int lane = t & 63, wid = t >> 6;
    int cq = lane >> 4, cr = lane & 15;
    bf16x8 wf[2][4];
    load_wfrags(W, cq, cr, wf);
    int rowbase = (blockIdx.x * 4 + wid) * 16;
    if (rowbase >= nrows) return;
    int arow = rowbase + cr; if (arow >= nrows) arow = nrows - 1;
    const float* xr = X + (size_t)arow * 64;
    bf16x8 af[2];
    #pragma unroll
    for (int ks = 0; ks < 2; ++ks) {
        const float4* p = (const float4*)(xr + ks * 32 + cq * 8);
        float4 a = p[0], b = p[1];
        bf16x8 v;
        v[0] = (short)f2bf(a.x); v[1] = (short)f2bf(a.y);
        v[2] = (short)f2bf(a.z); v[3] = (short)f2bf(a.w);
        v[4] = (short)f2bf(b.x); v[5] = (short)f2bf(b.y);
        v[6] = (short)f2bf(b.z); v[7] = (short)f2bf(b.w);
        af[ks] = v;
    }
    f32x4 z = {0.0f, 0.0f, 0.0f, 0.0f};
    f32x4 acc[4] = {z, z, z, z};
    #pragma unroll
    for (int ks = 0; ks < 2; ++ks)
        #pragma unroll
        for (int cb = 0; cb < 4; ++cb)
            acc[cb] = __builtin_amdgcn_mfma_f32_16x16x32_bf16(af[ks], wf[ks][cb],
                                                              acc[cb], 0, 0, 0);
    mfma_store(acc, dinv, Y, rowbase, cq, cr, nrows);
}

// conv2: X bf16, fused relu(X + bin)
__global__ __launch_bounds__(256) void lin64_mfma_bf16(const unsigned short* __restrict__ X,
                                                       const float* __restrict__ bin,
                                                       const float* __restrict__ W,
                                                       const float* __restrict__ dinv,
                                                       unsigned short* __restrict__ Y,
                                                       int nrows) {
    int t = threadIdx.x;
    int lane = t & 63, wid = t >> 6;
    int cq = lane >> 4, cr = lane & 15;
    bf16x8 wf[2][4];
    load_wfrags(W, cq, cr, wf);
    float bpre[2][8];
    #pragma unroll
    for (int ks = 0; ks < 2; ++ks)
        #pragma unroll
        for (int j = 0; j < 8; ++j)
            bpre[ks][j] = bin[ks * 32 + cq * 8 + j];
    int rowbase = (blockIdx.x * 4 + wid) * 16;
    if (rowbase >= nrows) return;
    int arow = rowbase + cr; if (arow >= nrows) arow = nrows - 1;
    const unsigned short* xr = X + (size_t)arow * 64;
    bf16x8 af[2];
    #pragma unroll
    for (int ks = 0; ks < 2; ++ks) {
        bf16x8 raw = *(const bf16x8*)(xr + ks * 32 + cq * 8);
        bf16x8 v;
        #pragma unroll
        for (int j = 0; j < 8; ++j) {
            float vv = bf2f((unsigned short)raw[j]) + bpre[ks][j];
            v[j] = (short)f2bf(fmaxf(vv, 0.0f));
        }
        af[ks] = v;
    }
    f32x4 z = {0.0f, 0.0f, 0.0f, 0.0f};
    f32x4 acc[4] = {z, z, z, z};
    #pragma unroll
    for (int ks = 0; ks < 2; ++ks)
        #pragma unroll
        for (int cb = 0; cb < 4; ++cb)
            acc[cb] = __builtin_amdgcn_mfma_f32_16x16x32_bf16(af[ks], wf[ks][cb],
                                                              acc[cb], 0, 0, 0);
    mfma_store(acc, dinv, Y, rowbase, cq, cr, nrows);
}

// ---------------- gather / pool / head -------------------------------------

__global__ __launch_bounds__(256) void gcn_gather(const __hip_bfloat16* __restrict__ A,
                                                  const float* __restrict__ dinv,
                                                  const int* __restrict__ rowptr,
                                                  const int* __restrict__ csr_src,
                                                  __hip_bfloat16* __restrict__ B, int n) {
    int t = threadIdx.x;
    int node = blockIdx.x * 4 + (t >> 6);
    int c = t & 63;
    if (node >= n) return;
    float acc = __bfloat162float(A[(size_t)node * 64 + c]);   // self loop
    int beg = rowptr[node], end = rowptr[node + 1];
    for (int chunk = beg; chunk < end; chunk += 64) {
        int m = end - chunk;
        if (m > 64) m = 64;
        int sl = (c < m) ? csr_src[chunk + c] : 0;            // coalesced
        int j = 0;
        for (; j + 4 <= m; j += 4) {
            int s0 = __shfl(sl, j);
            int s1 = __shfl(sl, j + 1);
            int s2 = __shfl(sl, j + 2);
            int s3 = __shfl(sl, j + 3);
            float v0 = __bfloat162float(A[(size_t)s0 * 64 + c]);
            float v1 = __bfloat162float(A[(size_t)s1 * 64 + c]);
            float v2 = __bfloat162float(A[(size_t)s2 * 64 + c]);
            float v3 = __bfloat162float(A[(size_t)s3 * 64 + c]);
            acc += (v0 + v1) + (v2 + v3);
        }
        for (; j < m; ++j) {
            int s = __shfl(sl, j);
            acc += __bfloat162float(A[(size_t)s * 64 + c]);
        }
    }
    B[(size_t)node * 64 + c] = __float2bfloat16(acc * dinv[node]);
}

#define POOL_NPW 32
__global__ __launch_bounds__(256) void pool_seg(const __hip_bfloat16* __restrict__ X,
                                                const float* __restrict__ b,
                                                const void* __restrict__ batch,
                                                const int* __restrict__ flag,
                                                float* __restrict__ sums,
                                                float* __restrict__ counts, int n) {
    int t = threadIdx.x;
    int c = t & 63;
    int wid = blockIdx.x * 4 + (t >> 6);
    int s0 = wid * POOL_NPW;
    if (s0 >= n) return;
    int s1 = s0 + POOL_NPW; if (s1 > n) s1 = n;
    int is64 = flag[0];
    float bc = b[c];
    float acc = 0.0f, cnt = 0.0f;
    int cur = idx_at(batch, s0, is64);
    int i = s0;
    for (; i + 2 <= s1; i += 2) {
        int g0 = idx_at(batch, i, is64);
        int g1 = idx_at(batch, i + 1, is64);
        float v0 = __bfloat162float(X[(size_t)i * 64 + c]);
        float v1 = __bfloat162float(X[(size_t)(i + 1) * 64 + c]);
        if (g0 != cur) {
            atomicAdd(&sums[(size_t)cur * 64 + c], acc);
            if (c == 0) atomicAdd(&counts[cur], cnt);
            acc = 0.0f; cnt = 0.0f; cur = g0;
        }
        acc += fmaxf(v0 + bc, 0.0f); cnt += 1.0f;
        if (g1 != cur) {
            atomicAdd(&sums[(size_t)cur * 64 + c], acc);
            if (c == 0) atomicAdd(&counts[cur], cnt);
            acc = 0.0f; cnt = 0.0f; cur = g1;
        }
        acc += fmaxf(v1 + bc, 0.0f); cnt += 1.0f;
    }
    if (i < s1) {
        int g0 = idx_at(batch, i, is64);
        float v0 = __bfloat162float(X[(size_t)i * 64 + c]);
        if (g0 != cur) {
            atomicAdd(&sums[(size_t)cur * 64 + c], acc);
            if (c == 0) atomicAdd(&counts[cur], cnt);
            acc = 0.0f; cnt = 0.0f; cur = g0;
        }
        acc += fmaxf(v0 + bc, 0.0f); cnt += 1.0f;
    }
    atomicAdd(&sums[(size_t)cur * 64 + c], acc);
    if (c == 0) atomicAdd(&counts[cur], cnt);
}

__global__ __launch_bounds__(64) void vae_head(const float* __restrict__ sums,
                                               const float* __restrict__ counts,
                                               const float* __restrict__ Wmu,
                                               const float* __restrict__ bmu,
                                               const float* __restrict__ Wlv,
                                               const float* __restrict__ blv,
                                               const float* __restrict__ Wd1,
                                               const float* __restrict__ bd1,
                                               const float* __restrict__ Wd2,
                                               const float* __restrict__ bd2,
                                               float* __restrict__ out) {
    int g = blockIdx.x;
    int t = threadIdx.x;  // 64 threads
    __shared__ float sp[64];
    __shared__ float sz[32];
    __shared__ float sh[64];

    float cnt = fmaxf(counts[g], 1.0f);
    sp[t] = sums[(size_t)g * 64 + t] / cnt;
    __syncthreads();

    if (t < 32) {
        float mu = bmu[t];
        float lv = blv[t];
        #pragma unroll
        for (int k = 0; k < 64; ++k) {
            float pk = sp[k];
            mu = fmaf(pk, Wmu[k * 32 + t], mu);
            lv = fmaf(pk, Wlv[k * 32 + t], lv);
        }
        unsigned idx = (unsigned)(g * 32 + t);
        float eps = jax_normal_4232(idx);
        float z = fmaf(eps, expf(0.5f * lv), mu);
        sz[t] = z;
        out[16384 + (size_t)g * 32 + t] = mu;       // mu block
        out[24576 + (size_t)g * 32 + t] = lv;       // logvar block
    }
    __syncthreads();

    float h = bd1[t];
    #pragma unroll
    for (int k = 0; k < 32; ++k) h = fmaf(sz[k], Wd1[k * 64 + t], h);
    h = fmaxf(h, 0.0f);
    sh[t] = h;
    __syncthreads();

    float r = bd2[t];
    #pragma unroll
    for (int k = 0; k < 64; ++k) r = fmaf(sh[k], Wd2[k * 64 + t], r);
    out[(size_t)g * 64 + t] = r;                    // recon block
}

// ---------------- launch ----------------------------------------------------

extern "C" void kernel_launch(void* const* d_in, const int* in_sizes, int n_in,
                              void* d_out, int out_size, void* d_ws, size_t ws_size,
                              hipStream_t stream) {
    const float* x    = (const float*)d_in[0];
    const void*  ei   = d_in[1];
    const void*  batch= d_in[2];
    const float* W1   = (const float*)d_in[3];
    const float* b1   = (const float*)d_in[4];
    const float* W2   = (const float*)d_in[5];
    const float* b2   = (const float*)d_in[6];
    const float* Wmu  = (const float*)d_in[7];
    const float* bmu  = (const float*)d_in[8];
    const float* Wlv  = (const float*)d_in[9];
    const float* blv  = (const float*)d_in[10];
    const float* Wd1  = (const float*)d_in[11];
    const float* bd1  = (const float*)d_in[12];
    const float* Wd2  = (const float*)d_in[13];
    const float* bd2  = (const float*)d_in[14];

    const int N = in_sizes[0] / 64;       // 100000
    const int E = in_sizes[1] / 2;        // 1000000
    const int G = 256;

    const int NPB = (N + NBK - 1) / NBK;          // 391 nodes per bucket
    const int nbu = (N + NPB - 1) / NPB;          // 256 buckets

    float* out = (float*)d_out;

    // workspace layout
    float* dinv = (float*)d_ws;                          // Npad floats
    __hip_bfloat16* A = (__hip_bfloat16*)(dinv + ((N + 255) & ~255)); // N*64 bf16
    __hip_bfloat16* B = A + (size_t)N * 64;              // N*64 bf16
    float* sums = (float*)(B + (size_t)N * 64);          // G*64
    float* cnts = sums + (size_t)G * 64;                 // G
    int*   flag = (int*)(cnts + G);                      // 1 (+pad to 256)
    int*   rowptr = flag + 256;                          // N+1 (+pad)
    int*   bcnt = rowptr + ((N + 256) & ~255);           // 256
    int*   ebase = bcnt + 256;                           // 257 (+pad)
    int*   gcur = ebase + 512;                           // 256
    int*   csr_src = gcur + 256;                         // E
    int2*  pairs = (int2*)(csr_src + ((E + 1) & ~1));    // E (8B aligned)

    const int blkRows  = (N + 3) / 4;
    const int blkLin   = (N + 63) / 64;                  // 16 rows/wave, 4 waves/blk
    const int blkPool  = (N + POOL_NPW * 4 - 1) / (POOL_NPW * 4);
    const int chunkE   = (E + NBK - 1) / NBK;            // edges per fill block

    // index dtype detection
    detect_idx64<<<1, 256, 0, stream>>>((const unsigned*)ei, E, flag);

    // bucketed CSR build
    hipMemsetAsync(bcnt, 0, NBK * sizeof(int), stream);
    bucket_count<<<NBK, 256, 0, stream>>>(ei, flag, bcnt, E, NPB, chunkE);
    bucket_scan<<<1, NBK, 0, stream>>>(bcnt, ebase, gcur, nbu, E);
    bucket_fill<<<NBK, 256, 0, stream>>>(ei, flag, gcur, pairs, E, NPB, chunkE);
    csr_build<<<nbu, 256, 0, stream>>>(pairs, ebase, rowptr, dinv, csr_src,
                                       N, E, NPB);

    // conv1: A = bf16(x@W1 * dinv) ; B = bf16(gather(A) * dinv)
    lin64_mfma_f32<<<blkLin, 256, 0, stream>>>(x, W1, dinv, (unsigned short*)A, N);
    gcn_gather<<<blkRows, 256, 0, stream>>>(A, dinv, rowptr, csr_src, B, N);

    // conv2: A = bf16(relu(B+b1)@W2 * dinv) ; B = bf16(gather(A) * dinv)
    lin64_mfma_bf16<<<blkLin, 256, 0, stream>>>((const unsigned short*)B, b1, W2,
                                                dinv, (unsigned short*)A, N);
    gcn_gather<<<blkRows, 256, 0, stream>>>(A, dinv, rowptr, csr_src, B, N);

    // pool (applies relu(B+b2)) + head
    hipMemsetAsync(sums, 0, (size_t)(G * 64 + G) * sizeof(float), stream);
    pool_seg<<<blkPool, 256, 0, stream>>>(B, b2, batch, flag, sums, cnts, N);
    vae_head<<<G, 64, 0, stream>>>(sums, cnts, Wmu, bmu, Wlv, blv,
                                   Wd1, bd1, Wd2, bd2, out);
}